// Round 1
// baseline (13253.983 us; speedup 1.0000x reference)
//
#include <hip/hip_runtime.h>
#include <cstddef>

#define HW96 9216
#define FRAME (64 * 9216)

// ---------------------------------------------------------------------------
// Weight repack: OIHW (O,I,3,3) -> [i][tap][o] contiguous in o, so the conv
// inner loop reads weights at uniform, contiguous scalar addresses (s_load).
// ---------------------------------------------------------------------------
__global__ __launch_bounds__(256) void repack_k(const float* __restrict__ w,
                                                float* __restrict__ wp,
                                                int O, int I, int T) {
    int idx = blockIdx.x * 256 + threadIdx.x;
    int total = O * I * T;
    if (idx >= total) return;
    int o = idx % O;
    int it = idx / O;
    int t = it % T;
    int i = it / T;
    wp[idx] = w[(o * I + i) * T + t];
}

// ---------------------------------------------------------------------------
// Direct 3x3 conv, SAME pad, stride 1. Up to 3 input sources of 64 channels
// each (nullptr == zeros). Tile 32x4 px, 128 threads, COT out-ch per thread.
// wp layout: [cin][tap][Cout]. Optional lrelu and residual-add.
// ---------------------------------------------------------------------------
template <int COT>
__global__ __launch_bounds__(128) void conv3x3_k(
    const float* __restrict__ s0, const float* __restrict__ s1,
    const float* __restrict__ s2, const float* __restrict__ wp,
    const float* __restrict__ bias, const float* __restrict__ addsrc,
    float* __restrict__ out, int cinTotal, int Cout, int act) {
    const int tx = threadIdx.x & 31;
    const int ty = threadIdx.x >> 5;
    const int px0 = blockIdx.x * 32;
    const int py0 = blockIdx.y * 4;
    const int obase = blockIdx.z * COT;
    const int px = px0 + tx, py = py0 + ty;
    const int pidx = py * 96 + px;

    __shared__ float lds[8][6][36];  // [chunk-ch][row 6][col 34 (+2 pad)]

    float acc[COT];
#pragma unroll
    for (int o = 0; o < COT; ++o) acc[o] = 0.f;

    const int nchunks = cinTotal >> 3;
    for (int cc = 0; cc < nchunks; ++cc) {
        const int cbase = cc << 3;
        const float* src = (cbase < 64) ? s0 : (cbase < 128 ? s1 : s2);
        if (src == nullptr) continue;  // uniform across block
        __syncthreads();
        for (int e = threadIdx.x; e < 8 * 204; e += 128) {
            int c = e / 204;
            int rem = e - c * 204;
            int r = rem / 34;
            int col = rem - r * 34;
            int gy = py0 - 1 + r;
            int gx = px0 - 1 + col;
            float v = 0.f;
            if ((unsigned)gy < 96u && (unsigned)gx < 96u)
                v = src[(size_t)((cbase & 63) + c) * HW96 + gy * 96 + gx];
            lds[c][r][col] = v;
        }
        __syncthreads();
#pragma unroll
        for (int c = 0; c < 8; ++c) {
            float v[9];
#pragma unroll
            for (int ky = 0; ky < 3; ++ky)
#pragma unroll
                for (int kx = 0; kx < 3; ++kx)
                    v[ky * 3 + kx] = lds[c][ty + ky][tx + kx];
            const float* wrow = wp + (size_t)((cbase + c) * 9) * Cout + obase;
#pragma unroll
            for (int t = 0; t < 9; ++t) {
                float vv = v[t];
#pragma unroll
                for (int o = 0; o < COT; ++o)
                    acc[o] = fmaf(wrow[t * Cout + o], vv, acc[o]);
            }
        }
    }
#pragma unroll
    for (int o = 0; o < COT; ++o) {
        float v = acc[o] + bias[obase + o];
        if (act) v = (v >= 0.f) ? v : 0.1f * v;
        if (addsrc) v += addsrc[(size_t)(obase + o) * HW96 + pidx];
        out[(size_t)(obase + o) * HW96 + pidx] = v;
    }
}

// ---------------------------------------------------------------------------
// Modulated deformable conv v2, 3x3, dg=16 groups, cpg=8.
// sA = channels 0..63 (prop), sB = channels 64..127 (feat_n2, may be null).
// raw = conv4 output (432 ch): offsets (tanh*5) + mask (sigmoid) fused here.
// wdp layout: [i=g*8+c][k][64]. 16 out-ch per block (z=4).
// ---------------------------------------------------------------------------
__global__ __launch_bounds__(128) void dconv_k(
    const float* __restrict__ sA, const float* __restrict__ sB,
    const float* __restrict__ raw, const float* __restrict__ wdp,
    const float* __restrict__ dbias, float* __restrict__ out) {
    const int tx = threadIdx.x & 31;
    const int ty = threadIdx.x >> 5;
    const int px = blockIdx.x * 32 + tx;
    const int py = blockIdx.y * 4 + ty;
    const int obase = blockIdx.z * 16;
    const int pidx = py * 96 + px;

    float acc[16];
#pragma unroll
    for (int o = 0; o < 16; ++o) acc[o] = 0.f;

    const int ngroups = (sB != nullptr) ? 16 : 8;
    for (int g = 0; g < ngroups; ++g) {
        const float* src = (g < 8) ? sA : sB;
        const int cb = (g & 7) * 8;
#pragma unroll
        for (int k = 0; k < 9; ++k) {
            const int ky = k / 3, kx = k % 3;
            float ry = raw[(size_t)(g * 18 + k * 2 + 0) * HW96 + pidx];
            float rx = raw[(size_t)(g * 18 + k * 2 + 1) * HW96 + pidx];
            float rm = raw[(size_t)(288 + g * 9 + k) * HW96 + pidx];
            // offset = 5*tanh(ry), tanh(x) = 1 - 2/(1+exp(2x)) (overflow-safe)
            float oy = 5.f * (1.f - 2.f / (1.f + __expf(2.f * ry)));
            float ox = 5.f * (1.f - 2.f / (1.f + __expf(2.f * rx)));
            float m = 1.f / (1.f + __expf(-rm));
            float sy = oy + (float)(py - 1 + ky);
            float sx = ox + (float)(px - 1 + kx);
            float fy0 = floorf(sy), fx0 = floorf(sx);
            float fy = sy - fy0, fx = sx - fx0;
            int y0 = (int)fy0, x0 = (int)fx0;
            int y1 = y0 + 1, x1 = x0 + 1;
            bool vy0 = (unsigned)y0 < 96u, vy1 = (unsigned)y1 < 96u;
            bool vx0 = (unsigned)x0 < 96u, vx1 = (unsigned)x1 < 96u;
            int cy0 = min(max(y0, 0), 95), cy1 = min(max(y1, 0), 95);
            int cx0 = min(max(x0, 0), 95), cx1 = min(max(x1, 0), 95);
            float w00 = (1.f - fy) * (1.f - fx) * ((vy0 && vx0) ? 1.f : 0.f);
            float w01 = (1.f - fy) * fx * ((vy0 && vx1) ? 1.f : 0.f);
            float w10 = fy * (1.f - fx) * ((vy1 && vx0) ? 1.f : 0.f);
            float w11 = fy * fx * ((vy1 && vx1) ? 1.f : 0.f);
            int i00 = cy0 * 96 + cx0, i01 = cy0 * 96 + cx1;
            int i10 = cy1 * 96 + cx0, i11 = cy1 * 96 + cx1;
#pragma unroll
            for (int c = 0; c < 8; ++c) {
                const float* plane = src + (size_t)(cb + c) * HW96;
                float v = w00 * plane[i00] + w01 * plane[i01] +
                          w10 * plane[i10] + w11 * plane[i11];
                float col = v * m;
                const float* wc = wdp + (size_t)((g * 8 + c) * 9 + k) * 64 + obase;
#pragma unroll
                for (int o = 0; o < 16; ++o)
                    acc[o] = fmaf(wc[o], col, acc[o]);
            }
        }
    }
#pragma unroll
    for (int o = 0; o < 16; ++o)
        out[(size_t)(obase + o) * HW96 + pidx] = acc[o] + dbias[obase + o];
}

// ---------------------------------------------------------------------------
// Fusion: 1x1 conv over concat([featB[t], featF[t]]) + bias + x, all 8 frames.
// wp layout: [i(128)][o(64)]. grid z = t*4 + (obase/16).
// ---------------------------------------------------------------------------
__global__ __launch_bounds__(128) void fuse_k(
    const float* __restrict__ featB, const float* __restrict__ featF,
    const float* __restrict__ x, const float* __restrict__ wp,
    const float* __restrict__ bias, float* __restrict__ out) {
    const int tx = threadIdx.x & 31;
    const int ty = threadIdx.x >> 5;
    const int px = blockIdx.x * 32 + tx;
    const int py = blockIdx.y * 4 + ty;
    const int t = blockIdx.z >> 2;
    const int obase = (blockIdx.z & 3) * 16;
    const int pidx = py * 96 + px;
    const float* fB = featB + (size_t)t * FRAME;
    const float* fF = featF + (size_t)t * FRAME;

    float acc[16];
#pragma unroll
    for (int o = 0; o < 16; ++o) acc[o] = 0.f;

    for (int i = 0; i < 64; ++i) {
        float v = fB[(size_t)i * HW96 + pidx];
        const float* wr = wp + i * 64 + obase;
#pragma unroll
        for (int o = 0; o < 16; ++o) acc[o] = fmaf(wr[o], v, acc[o]);
    }
    for (int i = 0; i < 64; ++i) {
        float v = fF[(size_t)i * HW96 + pidx];
        const float* wr = wp + (64 + i) * 64 + obase;
#pragma unroll
        for (int o = 0; o < 16; ++o) acc[o] = fmaf(wr[o], v, acc[o]);
    }
    const float* xt = x + (size_t)t * FRAME;
#pragma unroll
    for (int o = 0; o < 16; ++o)
        out[(size_t)t * FRAME + (size_t)(obase + o) * HW96 + pidx] =
            acc[o] + bias[obase + o] + xt[(size_t)(obase + o) * HW96 + pidx];
}

// ---------------------------------------------------------------------------
extern "C" void kernel_launch(void* const* d_in, const int* in_sizes, int n_in,
                              void* d_out, int out_size, void* d_ws,
                              size_t ws_size, hipStream_t stream) {
    const float* x = (const float*)d_in[0];
    auto gp = [&](int i) { return (const float*)d_in[i]; };

    struct DirP {
        const float *dw, *db, *ow1, *ob1, *ow2, *ob2, *ow3, *ob3, *ow4, *ob4,
            *bw1, *bb1, *bw2, *bb2;
    };
    DirP Pb{gp(1), gp(2), gp(3), gp(4), gp(5), gp(6), gp(7),
            gp(8), gp(9), gp(10), gp(11), gp(12), gp(13), gp(14)};
    DirP Pf{gp(15), gp(16), gp(17), gp(18), gp(19), gp(20), gp(21),
            gp(22), gp(23), gp(24), gp(25), gp(26), gp(27), gp(28)};
    const float* fus_w = gp(29);
    const float* fus_b = gp(30);

    float* ws = (float*)d_ws;
    float* featB = ws;                 // 8 frames
    float* featF = ws + (size_t)8 * FRAME;   // 8 frames
    float* Dbuf = ws + (size_t)16 * FRAME;   // deform output
    float* hA = ws + (size_t)17 * FRAME;
    float* hB = ws + (size_t)18 * FRAME;
    float* b432 = ws + (size_t)19 * FRAME;   // 432*9216
    float* wptr = b432 + (size_t)432 * HW96;
    auto alloc = [&](size_t n) { float* p = wptr; wptr += n; return p; };

    struct DirW { float *dw, *ow1, *ow2, *ow3, *ow4, *bw1, *bw2; };
    auto repack = [&](const float* src, int O, int I, int T) {
        float* dst = alloc((size_t)O * I * T);
        int total = O * I * T;
        repack_k<<<(total + 255) / 256, 256, 0, stream>>>(src, dst, O, I, T);
        return dst;
    };

    DirW Wb, Wf;
    Wb.dw = repack(Pb.dw, 64, 128, 9);
    Wb.ow1 = repack(Pb.ow1, 64, 192, 9);
    Wb.ow2 = repack(Pb.ow2, 64, 64, 9);
    Wb.ow3 = repack(Pb.ow3, 64, 64, 9);
    Wb.ow4 = repack(Pb.ow4, 432, 64, 9);
    Wb.bw1 = repack(Pb.bw1, 64, 128, 9);
    Wb.bw2 = repack(Pb.bw2, 64, 64, 9);
    Wf.dw = repack(Pf.dw, 64, 128, 9);
    Wf.ow1 = repack(Pf.ow1, 64, 192, 9);
    Wf.ow2 = repack(Pf.ow2, 64, 64, 9);
    Wf.ow3 = repack(Pf.ow3, 64, 64, 9);
    Wf.ow4 = repack(Pf.ow4, 432, 64, 9);
    Wf.bw1 = repack(Pf.bw1, 64, 192, 9);
    Wf.bw2 = repack(Pf.bw2, 64, 64, 9);
    float* Wfus = repack(fus_w, 64, 128, 1);

    auto conv = [&](const float* s0, const float* s1, const float* s2, int cin,
                    const float* wp, const float* bias, int cout, int act,
                    const float* addsrc, float* out) {
        if (cout == 432) {
            dim3 grid(3, 24, 27);
            conv3x3_k<16><<<grid, 128, 0, stream>>>(s0, s1, s2, wp, bias,
                                                    addsrc, out, cin, cout, act);
        } else {
            dim3 grid(3, 24, 8);
            conv3x3_k<8><<<grid, 128, 0, stream>>>(s0, s1, s2, wp, bias,
                                                   addsrc, out, cin, cout, act);
        }
    };

    for (int dir = 0; dir < 2; ++dir) {  // 0 = backward, 1 = forward
        const DirP& P = dir ? Pf : Pb;
        const DirW& Wd = dir ? Wf : Wb;
        float* feat = dir ? featF : featB;
        const float* prev1 = nullptr;
        const float* prev2 = nullptr;
        for (int i = 0; i < 8; ++i) {
            int idx = dir ? i : 7 - i;
            const float* cur = x + (size_t)idx * FRAME;
            const float* prop = prev1;
            if (i > 0) {
                // cond = [prop, cur, feat_n2] -> offset/mask net
                conv(prop, cur, prev2, 192, Wd.ow1, P.ob1, 64, 1, nullptr, hA);
                conv(hA, nullptr, nullptr, 64, Wd.ow2, P.ob2, 64, 1, nullptr, hB);
                conv(hB, nullptr, nullptr, 64, Wd.ow3, P.ob3, 64, 1, nullptr, hA);
                conv(hA, nullptr, nullptr, 64, Wd.ow4, P.ob4, 432, 0, nullptr, b432);
                dim3 dg(3, 24, 4);
                dconv_k<<<dg, 128, 0, stream>>>(prop, prev2, b432, Wd.dw, P.db,
                                                Dbuf);
                prop = Dbuf;
            }
            float* dst = feat + (size_t)idx * FRAME;
            if (dir == 0) {
                conv(cur, prop, nullptr, 128, Wd.bw1, P.bb1, 64, 1, nullptr, hB);
            } else {
                conv(cur, featB + (size_t)idx * FRAME, prop, 192, Wd.bw1, P.bb1,
                     64, 1, nullptr, hB);
            }
            conv(hB, nullptr, nullptr, 64, Wd.bw2, P.bb2, 64, 0, prop, dst);
            prev2 = prev1;
            prev1 = dst;
        }
    }

    dim3 fg(3, 24, 32);
    fuse_k<<<fg, 128, 0, stream>>>(featB, featF, x, Wfus, fus_b, (float*)d_out);
}

// Round 2
// 11992.704 us; speedup vs baseline: 1.1052x; 1.1052x over previous
//
#include <hip/hip_runtime.h>
#include <cstddef>

#define HW96 9216
#define FRAME (64 * 9216)

// ---------------------------------------------------------------------------
// Weight repack (all tensors in ONE launch): OIHW -> [i][tap][o].
// ---------------------------------------------------------------------------
struct RepackJob {
    const float* src;
    float* dst;
    int O, I, T;
};
struct RepackJobs {
    RepackJob j[15];
};

__global__ __launch_bounds__(256) void repack_all_k(RepackJobs jobs) {
    const RepackJob& J = jobs.j[blockIdx.y];
    int idx = blockIdx.x * 256 + threadIdx.x;
    int total = J.O * J.I * J.T;
    if (idx >= total) return;
    int o = idx % J.O;
    int it = idx / J.O;
    int t = it % J.T;
    int i = it / J.T;
    J.dst[idx] = J.src[(o * J.I + i) * J.T + t];
}

// ---------------------------------------------------------------------------
// Direct 3x3 conv, SAME pad. Compacted source list (no nulls): nsrc sources of
// 64 ch each, per-source weight base W[j] = wp + 64*pos_j*9*Cout.
// Tile 32x8 px, 256 threads, COT out-ch per thread. Software-pipelined
// staging: next chunk's global loads issued before current chunk's FMAs.
// ---------------------------------------------------------------------------
template <int COT>
__global__ __launch_bounds__(256) void conv3x3_k(
    const float* __restrict__ s0, const float* __restrict__ s1,
    const float* __restrict__ s2, const float* __restrict__ w0,
    const float* __restrict__ w1, const float* __restrict__ w2,
    const float* __restrict__ bias, const float* __restrict__ addsrc,
    float* __restrict__ out, int nsrc, int Cout, int act) {
    const int tx = threadIdx.x & 31;
    const int ty = threadIdx.x >> 5;  // 0..7
    const int px0 = blockIdx.x * 32;
    const int py0 = blockIdx.y * 8;
    const int obase = blockIdx.z * COT;
    const int px = px0 + tx, py = py0 + ty;
    const int pidx = py * 96 + px;

    __shared__ float lds[8 * 10 * 34];  // 8 ch x 10 rows x 34 cols = 2720

    float acc[COT];
#pragma unroll
    for (int o = 0; o < COT; ++o) acc[o] = 0.f;

    const int nchunks = nsrc * 8;
    float rg[11];

    // ---- load chunk 0 into regs ----
    {
        const float* src = s0;
        const int cb = 0;
#pragma unroll
        for (int it = 0; it < 11; ++it) {
            int e = threadIdx.x + it * 256;
            float v = 0.f;
            if (e < 2720) {
                int c = e / 340;
                int rem = e - c * 340;
                int r = rem / 34;
                int col = rem - r * 34;
                int gy = py0 - 1 + r;
                int gx = px0 - 1 + col;
                if ((unsigned)gy < 96u && (unsigned)gx < 96u)
                    v = src[(size_t)(cb + c) * HW96 + gy * 96 + gx];
            }
            rg[it] = v;
        }
    }

    for (int cc = 0; cc < nchunks; ++cc) {
        __syncthreads();
#pragma unroll
        for (int it = 0; it < 11; ++it) {
            int e = threadIdx.x + it * 256;
            if (e < 2720) lds[e] = rg[it];
        }
        __syncthreads();
        // ---- issue next chunk's loads (overlap with FMAs below) ----
        if (cc + 1 < nchunks) {
            int nc = cc + 1;
            int j = nc >> 3;
            const float* src = (j == 0) ? s0 : (j == 1 ? s1 : s2);
            int cb = (nc & 7) * 8;
#pragma unroll
            for (int it = 0; it < 11; ++it) {
                int e = threadIdx.x + it * 256;
                float v = 0.f;
                if (e < 2720) {
                    int c = e / 340;
                    int rem = e - c * 340;
                    int r = rem / 34;
                    int col = rem - r * 34;
                    int gy = py0 - 1 + r;
                    int gx = px0 - 1 + col;
                    if ((unsigned)gy < 96u && (unsigned)gx < 96u)
                        v = src[(size_t)(cb + c) * HW96 + gy * 96 + gx];
                }
                rg[it] = v;
            }
        }
        // ---- compute current chunk from LDS ----
        int j = cc >> 3;
        const float* wj = (j == 0) ? w0 : (j == 1 ? w1 : w2);
        int cb = (cc & 7) * 8;
#pragma unroll
        for (int c = 0; c < 8; ++c) {
            float v[9];
#pragma unroll
            for (int ky = 0; ky < 3; ++ky)
#pragma unroll
                for (int kx = 0; kx < 3; ++kx)
                    v[ky * 3 + kx] = lds[c * 340 + (ty + ky) * 34 + (tx + kx)];
            const float* wr = wj + (size_t)((cb + c) * 9) * Cout + obase;
#pragma unroll
            for (int t = 0; t < 9; ++t) {
                float vv = v[t];
#pragma unroll
                for (int o = 0; o < COT; ++o)
                    acc[o] = fmaf(wr[t * Cout + o], vv, acc[o]);
            }
        }
    }
#pragma unroll
    for (int o = 0; o < COT; ++o) {
        float v = acc[o] + bias[obase + o];
        if (act) v = (v >= 0.f) ? v : 0.1f * v;
        if (addsrc) v += addsrc[(size_t)(obase + o) * HW96 + pidx];
        out[(size_t)(obase + o) * HW96 + pidx] = v;
    }
}

// ---------------------------------------------------------------------------
// Modulated deformable conv v2, 3x3, dg=16, cpg=8. Tile 32x8, 256 thr,
// 8 out-ch per thread (z=8). tanh/sigmoid fused.
// ---------------------------------------------------------------------------
__global__ __launch_bounds__(256) void dconv_k(
    const float* __restrict__ sA, const float* __restrict__ sB,
    const float* __restrict__ raw, const float* __restrict__ wdp,
    const float* __restrict__ dbias, float* __restrict__ out) {
    const int tx = threadIdx.x & 31;
    const int ty = threadIdx.x >> 5;
    const int px = blockIdx.x * 32 + tx;
    const int py = blockIdx.y * 8 + ty;
    const int obase = blockIdx.z * 8;
    const int pidx = py * 96 + px;

    float acc[8];
#pragma unroll
    for (int o = 0; o < 8; ++o) acc[o] = 0.f;

    const int ngroups = (sB != nullptr) ? 16 : 8;
    for (int g = 0; g < ngroups; ++g) {
        const float* src = (g < 8) ? sA : sB;
        const int cb = (g & 7) * 8;
#pragma unroll
        for (int k = 0; k < 9; ++k) {
            const int ky = k / 3, kx = k % 3;
            float ry = raw[(size_t)(g * 18 + k * 2 + 0) * HW96 + pidx];
            float rx = raw[(size_t)(g * 18 + k * 2 + 1) * HW96 + pidx];
            float rm = raw[(size_t)(288 + g * 9 + k) * HW96 + pidx];
            // offset = 5*tanh(r): tanh(x) = 1 - 2/(1+exp(2x)) (overflow-safe)
            float oy = 5.f * (1.f - 2.f / (1.f + __expf(2.f * ry)));
            float ox = 5.f * (1.f - 2.f / (1.f + __expf(2.f * rx)));
            float m = 1.f / (1.f + __expf(-rm));
            float sy = oy + (float)(py - 1 + ky);
            float sx = ox + (float)(px - 1 + kx);
            float fy0 = floorf(sy), fx0 = floorf(sx);
            float fy = sy - fy0, fx = sx - fx0;
            int y0 = (int)fy0, x0 = (int)fx0;
            int y1 = y0 + 1, x1 = x0 + 1;
            bool vy0 = (unsigned)y0 < 96u, vy1 = (unsigned)y1 < 96u;
            bool vx0 = (unsigned)x0 < 96u, vx1 = (unsigned)x1 < 96u;
            int cy0 = min(max(y0, 0), 95), cy1 = min(max(y1, 0), 95);
            int cx0 = min(max(x0, 0), 95), cx1 = min(max(x1, 0), 95);
            float w00 = (1.f - fy) * (1.f - fx) * ((vy0 && vx0) ? 1.f : 0.f);
            float w01 = (1.f - fy) * fx * ((vy0 && vx1) ? 1.f : 0.f);
            float w10 = fy * (1.f - fx) * ((vy1 && vx0) ? 1.f : 0.f);
            float w11 = fy * fx * ((vy1 && vx1) ? 1.f : 0.f);
            int i00 = cy0 * 96 + cx0, i01 = cy0 * 96 + cx1;
            int i10 = cy1 * 96 + cx0, i11 = cy1 * 96 + cx1;
#pragma unroll
            for (int c = 0; c < 8; ++c) {
                const float* plane = src + (size_t)(cb + c) * HW96;
                float v = w00 * plane[i00] + w01 * plane[i01] +
                          w10 * plane[i10] + w11 * plane[i11];
                float col = v * m;
                const float* wc = wdp + (size_t)((g * 8 + c) * 9 + k) * 64 + obase;
#pragma unroll
                for (int o = 0; o < 8; ++o)
                    acc[o] = fmaf(wc[o], col, acc[o]);
            }
        }
    }
#pragma unroll
    for (int o = 0; o < 8; ++o)
        out[(size_t)(obase + o) * HW96 + pidx] = acc[o] + dbias[obase + o];
}

// ---------------------------------------------------------------------------
// Fusion: 1x1 conv over [featB[t], featF[t]] + bias + x, all frames.
// grid z = t*8 + (obase/8).
// ---------------------------------------------------------------------------
__global__ __launch_bounds__(256) void fuse_k(
    const float* __restrict__ featB, const float* __restrict__ featF,
    const float* __restrict__ x, const float* __restrict__ wp,
    const float* __restrict__ bias, float* __restrict__ out) {
    const int tx = threadIdx.x & 31;
    const int ty = threadIdx.x >> 5;
    const int px = blockIdx.x * 32 + tx;
    const int py = blockIdx.y * 8 + ty;
    const int t = blockIdx.z >> 3;
    const int obase = (blockIdx.z & 7) * 8;
    const int pidx = py * 96 + px;
    const float* fB = featB + (size_t)t * FRAME;
    const float* fF = featF + (size_t)t * FRAME;

    float acc[8];
#pragma unroll
    for (int o = 0; o < 8; ++o) acc[o] = 0.f;

    for (int i = 0; i < 64; ++i) {
        float v = fB[(size_t)i * HW96 + pidx];
        const float* wr = wp + i * 64 + obase;
#pragma unroll
        for (int o = 0; o < 8; ++o) acc[o] = fmaf(wr[o], v, acc[o]);
    }
    for (int i = 0; i < 64; ++i) {
        float v = fF[(size_t)i * HW96 + pidx];
        const float* wr = wp + (64 + i) * 64 + obase;
#pragma unroll
        for (int o = 0; o < 8; ++o) acc[o] = fmaf(wr[o], v, acc[o]);
    }
    const float* xt = x + (size_t)t * FRAME;
#pragma unroll
    for (int o = 0; o < 8; ++o)
        out[(size_t)t * FRAME + (size_t)(obase + o) * HW96 + pidx] =
            acc[o] + bias[obase + o] + xt[(size_t)(obase + o) * HW96 + pidx];
}

// ---------------------------------------------------------------------------
extern "C" void kernel_launch(void* const* d_in, const int* in_sizes, int n_in,
                              void* d_out, int out_size, void* d_ws,
                              size_t ws_size, hipStream_t stream) {
    const float* x = (const float*)d_in[0];
    auto gp = [&](int i) { return (const float*)d_in[i]; };

    struct DirP {
        const float *dw, *db, *ow1, *ob1, *ow2, *ob2, *ow3, *ob3, *ow4, *ob4,
            *bw1, *bb1, *bw2, *bb2;
    };
    DirP Pb{gp(1), gp(2), gp(3), gp(4), gp(5), gp(6), gp(7),
            gp(8), gp(9), gp(10), gp(11), gp(12), gp(13), gp(14)};
    DirP Pf{gp(15), gp(16), gp(17), gp(18), gp(19), gp(20), gp(21),
            gp(22), gp(23), gp(24), gp(25), gp(26), gp(27), gp(28)};
    const float* fus_w = gp(29);
    const float* fus_b = gp(30);

    float* ws = (float*)d_ws;
    float* featB = ws;                       // 8 frames
    float* featF = ws + (size_t)8 * FRAME;   // 8 frames
    float* Dbuf = ws + (size_t)16 * FRAME;   // deform output
    float* hA = ws + (size_t)17 * FRAME;
    float* hB = ws + (size_t)18 * FRAME;
    float* b432 = ws + (size_t)19 * FRAME;   // 432*9216
    float* wptr = b432 + (size_t)432 * HW96;
    auto alloc = [&](size_t n) { float* p = wptr; wptr += n; return p; };

    RepackJobs jobs;
    int njobs = 0;
    auto repack = [&](const float* src, int O, int I, int T) {
        float* dst = alloc((size_t)O * I * T);
        jobs.j[njobs++] = RepackJob{src, dst, O, I, T};
        return dst;
    };

    struct DirW { float *dw, *ow1, *ow2, *ow3, *ow4, *bw1, *bw2; };
    DirW Wb, Wf;
    Wb.dw = repack(Pb.dw, 64, 128, 9);
    Wb.ow1 = repack(Pb.ow1, 64, 192, 9);
    Wb.ow2 = repack(Pb.ow2, 64, 64, 9);
    Wb.ow3 = repack(Pb.ow3, 64, 64, 9);
    Wb.ow4 = repack(Pb.ow4, 432, 64, 9);
    Wb.bw1 = repack(Pb.bw1, 64, 128, 9);
    Wb.bw2 = repack(Pb.bw2, 64, 64, 9);
    Wf.dw = repack(Pf.dw, 64, 128, 9);
    Wf.ow1 = repack(Pf.ow1, 64, 192, 9);
    Wf.ow2 = repack(Pf.ow2, 64, 64, 9);
    Wf.ow3 = repack(Pf.ow3, 64, 64, 9);
    Wf.ow4 = repack(Pf.ow4, 432, 64, 9);
    Wf.bw1 = repack(Pf.bw1, 64, 192, 9);
    Wf.bw2 = repack(Pf.bw2, 64, 64, 9);
    float* Wfus = repack(fus_w, 64, 128, 1);

    {
        dim3 rg(972, 15);  // 972*256 covers the largest job (432*64*9)
        repack_all_k<<<rg, 256, 0, stream>>>(jobs);
    }

    // conv launcher: compacts null sources, pairs each with its weight slice.
    auto conv = [&](const float* a, const float* b, const float* c2,
                    const float* wp, const float* bias, int cout, int act,
                    const float* addsrc, float* out) {
        const float* srcs[3] = {a, b, c2};
        const float* S[3] = {nullptr, nullptr, nullptr};
        const float* W[3] = {nullptr, nullptr, nullptr};
        int ns = 0;
        for (int j = 0; j < 3; ++j)
            if (srcs[j]) {
                S[ns] = srcs[j];
                W[ns] = wp + (size_t)(64 * j * 9) * cout;
                ++ns;
            }
        if (cout == 432) {
            dim3 grid(3, 12, 27);
            conv3x3_k<16><<<grid, 256, 0, stream>>>(S[0], S[1], S[2], W[0],
                                                    W[1], W[2], bias, addsrc,
                                                    out, ns, cout, act);
        } else {
            dim3 grid(3, 12, 8);
            conv3x3_k<8><<<grid, 256, 0, stream>>>(S[0], S[1], S[2], W[0], W[1],
                                                   W[2], bias, addsrc, out, ns,
                                                   cout, act);
        }
    };

    for (int dir = 0; dir < 2; ++dir) {  // 0 = backward, 1 = forward
        const DirP& P = dir ? Pf : Pb;
        const DirW& Wd = dir ? Wf : Wb;
        float* feat = dir ? featF : featB;
        const float* prev1 = nullptr;
        const float* prev2 = nullptr;
        for (int i = 0; i < 8; ++i) {
            int idx = dir ? i : 7 - i;
            const float* cur = x + (size_t)idx * FRAME;
            const float* prop = prev1;
            if (i > 0) {
                // cond = [prop, cur, feat_n2] -> offset/mask net
                conv(prop, cur, prev2, Wd.ow1, P.ob1, 64, 1, nullptr, hA);
                conv(hA, nullptr, nullptr, Wd.ow2, P.ob2, 64, 1, nullptr, hB);
                conv(hB, nullptr, nullptr, Wd.ow3, P.ob3, 64, 1, nullptr, hA);
                conv(hA, nullptr, nullptr, Wd.ow4, P.ob4, 432, 0, nullptr,
                     b432);
                dim3 dg(3, 12, 8);
                dconv_k<<<dg, 256, 0, stream>>>(prop, prev2, b432, Wd.dw, P.db,
                                                Dbuf);
                prop = Dbuf;
            }
            float* dst = feat + (size_t)idx * FRAME;
            if (dir == 0) {
                conv(cur, prop, nullptr, Wd.bw1, P.bb1, 64, 1, nullptr, hB);
            } else {
                conv(cur, featB + (size_t)idx * FRAME, prop, Wd.bw1, P.bb1, 64,
                     1, nullptr, hB);
            }
            conv(hB, nullptr, nullptr, Wd.bw2, P.bb2, 64, 0, prop, dst);
            prev2 = prev1;
            prev1 = dst;
        }
    }

    dim3 fg(3, 12, 64);
    fuse_k<<<fg, 256, 0, stream>>>(featB, featF, x, Wfus, fus_b,
                                   (float*)d_out);
}

// Round 3
// 6917.013 us; speedup vs baseline: 1.9161x; 1.7338x over previous
//
#include <hip/hip_runtime.h>
#include <cstddef>

#define HW96 9216
#define FRAME (64 * 9216)

// ---------------------------------------------------------------------------
// Weight repack (all tensors in ONE launch): OIHW -> [i][tap][o].
// ---------------------------------------------------------------------------
struct RepackJob {
    const float* src;
    float* dst;
    int O, I, T;
};
struct RepackJobs {
    RepackJob j[15];
};

__global__ __launch_bounds__(256) void repack_all_k(RepackJobs jobs) {
    const RepackJob& J = jobs.j[blockIdx.y];
    int idx = blockIdx.x * 256 + threadIdx.x;
    int total = J.O * J.I * J.T;
    if (idx >= total) return;
    int o = idx % J.O;
    int it = idx / J.O;
    int t = it % J.T;
    int i = it / J.T;
    J.dst[idx] = J.src[(o * J.I + i) * J.T + t];
}

// ---------------------------------------------------------------------------
// Direct 3x3 conv, SAME pad. Compacted source list (no nulls): nsrc sources of
// 64 ch each, per-source weight base. Tile 32x8 px, 256 threads, COT out-ch
// per thread, COUT compile-time. Software-pipelined staging.
// ---------------------------------------------------------------------------
template <int COT, int COUT>
__global__ __launch_bounds__(256) void conv3x3_k(
    const float* __restrict__ s0, const float* __restrict__ s1,
    const float* __restrict__ s2, const float* __restrict__ w0,
    const float* __restrict__ w1, const float* __restrict__ w2,
    const float* __restrict__ bias, const float* __restrict__ addsrc,
    float* __restrict__ out, int nsrc, int act) {
    const int tx = threadIdx.x & 31;
    const int ty = threadIdx.x >> 5;  // 0..7
    const int px0 = blockIdx.x * 32;
    const int py0 = blockIdx.y * 8;
    const int obase = blockIdx.z * COT;
    const int px = px0 + tx, py = py0 + ty;
    const int pidx = py * 96 + px;

    __shared__ float lds[8 * 10 * 34];  // 8 ch x 10 rows x 34 cols = 2720

    float acc[COT];
#pragma unroll
    for (int o = 0; o < COT; ++o) acc[o] = 0.f;

    const int nchunks = nsrc * 8;
    float rg[11];

    // ---- load chunk 0 into regs ----
    {
        const float* src = s0;
#pragma unroll
        for (int it = 0; it < 11; ++it) {
            int e = threadIdx.x + it * 256;
            float v = 0.f;
            if (e < 2720) {
                int c = e / 340;
                int rem = e - c * 340;
                int r = rem / 34;
                int col = rem - r * 34;
                int gy = py0 - 1 + r;
                int gx = px0 - 1 + col;
                if ((unsigned)gy < 96u && (unsigned)gx < 96u)
                    v = src[(size_t)c * HW96 + gy * 96 + gx];
            }
            rg[it] = v;
        }
    }

    for (int cc = 0; cc < nchunks; ++cc) {
        __syncthreads();
#pragma unroll
        for (int it = 0; it < 11; ++it) {
            int e = threadIdx.x + it * 256;
            if (e < 2720) lds[e] = rg[it];
        }
        __syncthreads();
        // ---- issue next chunk's loads (overlap with FMAs below) ----
        if (cc + 1 < nchunks) {
            int nc = cc + 1;
            int j = nc >> 3;
            const float* src = (j == 0) ? s0 : (j == 1 ? s1 : s2);
            int cb = (nc & 7) * 8;
#pragma unroll
            for (int it = 0; it < 11; ++it) {
                int e = threadIdx.x + it * 256;
                float v = 0.f;
                if (e < 2720) {
                    int c = e / 340;
                    int rem = e - c * 340;
                    int r = rem / 34;
                    int col = rem - r * 34;
                    int gy = py0 - 1 + r;
                    int gx = px0 - 1 + col;
                    if ((unsigned)gy < 96u && (unsigned)gx < 96u)
                        v = src[(size_t)(cb + c) * HW96 + gy * 96 + gx];
                }
                rg[it] = v;
            }
        }
        // ---- compute current chunk from LDS ----
        int j = cc >> 3;
        const float* wj = (j == 0) ? w0 : (j == 1 ? w1 : w2);
        int cb = (cc & 7) * 8;
#pragma unroll
        for (int c = 0; c < 8; ++c) {
            float v[9];
#pragma unroll
            for (int ky = 0; ky < 3; ++ky)
#pragma unroll
                for (int kx = 0; kx < 3; ++kx)
                    v[ky * 3 + kx] = lds[c * 340 + (ty + ky) * 34 + (tx + kx)];
            const float* wr = wj + (size_t)((cb + c) * 9) * COUT + obase;
#pragma unroll
            for (int t = 0; t < 9; ++t) {
                float vv = v[t];
#pragma unroll
                for (int o = 0; o < COT; ++o)
                    acc[o] = fmaf(wr[t * COUT + o], vv, acc[o]);
            }
        }
    }
#pragma unroll
    for (int o = 0; o < COT; ++o) {
        float v = acc[o] + bias[obase + o];
        if (act) v = (v >= 0.f) ? v : 0.1f * v;
        if (addsrc) v += addsrc[(size_t)(obase + o) * HW96 + pidx];
        out[(size_t)(obase + o) * HW96 + pidx] = v;
    }
}

// ---------------------------------------------------------------------------
// out[ch][pix] = bias[ch] (pre-init for dconv atomic accumulation)
// ---------------------------------------------------------------------------
__global__ __launch_bounds__(256) void binit_k(const float* __restrict__ bias,
                                               float* __restrict__ out) {
    int i = blockIdx.x * 256 + threadIdx.x;  // 64*9216 total
    out[i] = bias[i / HW96];
}

// ---------------------------------------------------------------------------
// Modulated deformable conv v2, split-G: one deform group per block-z.
// Each block computes its group's gathers ONCE and accumulates that group's
// contribution to ALL 64 out-channels in registers (weights via SGPRs), then
// atomically adds into the bias-pre-initialized output.
// ---------------------------------------------------------------------------
__global__ __launch_bounds__(256) void dconv_split_k(
    const float* __restrict__ sA, const float* __restrict__ sB,
    const float* __restrict__ raw, const float* __restrict__ wdp,
    float* __restrict__ out) {
    const int tx = threadIdx.x & 31;
    const int ty = threadIdx.x >> 5;
    const int px = blockIdx.x * 32 + tx;
    const int py = blockIdx.y * 8 + ty;
    const int pidx = py * 96 + px;
    const int g = blockIdx.z;
    const float* src = (g < 8) ? sA : sB;
    const int cb = (g & 7) * 8;

    float acc[64];
#pragma unroll
    for (int o = 0; o < 64; ++o) acc[o] = 0.f;

#pragma unroll
    for (int k = 0; k < 9; ++k) {
        const int ky = k / 3, kx = k % 3;
        float ry = raw[(size_t)(g * 18 + k * 2 + 0) * HW96 + pidx];
        float rx = raw[(size_t)(g * 18 + k * 2 + 1) * HW96 + pidx];
        float rm = raw[(size_t)(288 + g * 9 + k) * HW96 + pidx];
        // offset = 5*tanh(r): tanh(x) = 1 - 2/(1+exp(2x)) (overflow-safe)
        float oy = 5.f * (1.f - 2.f / (1.f + __expf(2.f * ry)));
        float ox = 5.f * (1.f - 2.f / (1.f + __expf(2.f * rx)));
        float m = 1.f / (1.f + __expf(-rm));
        float sy = oy + (float)(py - 1 + ky);
        float sx = ox + (float)(px - 1 + kx);
        float fy0 = floorf(sy), fx0 = floorf(sx);
        float fy = sy - fy0, fx = sx - fx0;
        int y0 = (int)fy0, x0 = (int)fx0;
        int y1 = y0 + 1, x1 = x0 + 1;
        bool vy0 = (unsigned)y0 < 96u, vy1 = (unsigned)y1 < 96u;
        bool vx0 = (unsigned)x0 < 96u, vx1 = (unsigned)x1 < 96u;
        int cy0 = min(max(y0, 0), 95), cy1 = min(max(y1, 0), 95);
        int cx0 = min(max(x0, 0), 95), cx1 = min(max(x1, 0), 95);
        float w00 = (1.f - fy) * (1.f - fx) * ((vy0 && vx0) ? 1.f : 0.f);
        float w01 = (1.f - fy) * fx * ((vy0 && vx1) ? 1.f : 0.f);
        float w10 = fy * (1.f - fx) * ((vy1 && vx0) ? 1.f : 0.f);
        float w11 = fy * fx * ((vy1 && vx1) ? 1.f : 0.f);
        int i00 = cy0 * 96 + cx0, i01 = cy0 * 96 + cx1;
        int i10 = cy1 * 96 + cx0, i11 = cy1 * 96 + cx1;
#pragma unroll
        for (int c = 0; c < 8; ++c) {
            const float* plane = src + (size_t)(cb + c) * HW96;
            float v = w00 * plane[i00] + w01 * plane[i01] +
                      w10 * plane[i10] + w11 * plane[i11];
            float col = v * m;
            const float* wc = wdp + (size_t)((g * 8 + c) * 9 + k) * 64;
#pragma unroll
            for (int o = 0; o < 64; ++o)
                acc[o] = fmaf(wc[o], col, acc[o]);
        }
    }
#pragma unroll
    for (int o = 0; o < 64; ++o)
        unsafeAtomicAdd(&out[(size_t)o * HW96 + pidx], acc[o]);
}

// ---------------------------------------------------------------------------
// Fusion: 1x1 conv over [featB[t], featF[t]] + bias + x, all frames.
// ---------------------------------------------------------------------------
__global__ __launch_bounds__(256) void fuse_k(
    const float* __restrict__ featB, const float* __restrict__ featF,
    const float* __restrict__ x, const float* __restrict__ wp,
    const float* __restrict__ bias, float* __restrict__ out) {
    const int tx = threadIdx.x & 31;
    const int ty = threadIdx.x >> 5;
    const int px = blockIdx.x * 32 + tx;
    const int py = blockIdx.y * 8 + ty;
    const int t = blockIdx.z >> 3;
    const int obase = (blockIdx.z & 7) * 8;
    const int pidx = py * 96 + px;
    const float* fB = featB + (size_t)t * FRAME;
    const float* fF = featF + (size_t)t * FRAME;

    float acc[8];
#pragma unroll
    for (int o = 0; o < 8; ++o) acc[o] = 0.f;

    for (int i = 0; i < 64; ++i) {
        float v = fB[(size_t)i * HW96 + pidx];
        const float* wr = wp + i * 64 + obase;
#pragma unroll
        for (int o = 0; o < 8; ++o) acc[o] = fmaf(wr[o], v, acc[o]);
    }
    for (int i = 0; i < 64; ++i) {
        float v = fF[(size_t)i * HW96 + pidx];
        const float* wr = wp + (64 + i) * 64 + obase;
#pragma unroll
        for (int o = 0; o < 8; ++o) acc[o] = fmaf(wr[o], v, acc[o]);
    }
    const float* xt = x + (size_t)t * FRAME;
#pragma unroll
    for (int o = 0; o < 8; ++o)
        out[(size_t)t * FRAME + (size_t)(obase + o) * HW96 + pidx] =
            acc[o] + bias[obase + o] + xt[(size_t)(obase + o) * HW96 + pidx];
}

// ---------------------------------------------------------------------------
extern "C" void kernel_launch(void* const* d_in, const int* in_sizes, int n_in,
                              void* d_out, int out_size, void* d_ws,
                              size_t ws_size, hipStream_t stream) {
    const float* x = (const float*)d_in[0];
    auto gp = [&](int i) { return (const float*)d_in[i]; };

    struct DirP {
        const float *dw, *db, *ow1, *ob1, *ow2, *ob2, *ow3, *ob3, *ow4, *ob4,
            *bw1, *bb1, *bw2, *bb2;
    };
    DirP Pb{gp(1), gp(2), gp(3), gp(4), gp(5), gp(6), gp(7),
            gp(8), gp(9), gp(10), gp(11), gp(12), gp(13), gp(14)};
    DirP Pf{gp(15), gp(16), gp(17), gp(18), gp(19), gp(20), gp(21),
            gp(22), gp(23), gp(24), gp(25), gp(26), gp(27), gp(28)};
    const float* fus_w = gp(29);
    const float* fus_b = gp(30);

    float* ws = (float*)d_ws;
    float* featB = ws;                       // 8 frames
    float* featF = ws + (size_t)8 * FRAME;   // 8 frames
    float* Dbuf = ws + (size_t)16 * FRAME;   // deform output
    float* hA = ws + (size_t)17 * FRAME;
    float* hB = ws + (size_t)18 * FRAME;
    float* b432 = ws + (size_t)19 * FRAME;   // 432*9216
    float* wptr = b432 + (size_t)432 * HW96;
    auto alloc = [&](size_t n) { float* p = wptr; wptr += n; return p; };

    RepackJobs jobs;
    int njobs = 0;
    auto repack = [&](const float* src, int O, int I, int T) {
        float* dst = alloc((size_t)O * I * T);
        jobs.j[njobs++] = RepackJob{src, dst, O, I, T};
        return dst;
    };

    struct DirW { float *dw, *ow1, *ow2, *ow3, *ow4, *bw1, *bw2; };
    DirW Wb, Wf;
    Wb.dw = repack(Pb.dw, 64, 128, 9);
    Wb.ow1 = repack(Pb.ow1, 64, 192, 9);
    Wb.ow2 = repack(Pb.ow2, 64, 64, 9);
    Wb.ow3 = repack(Pb.ow3, 64, 64, 9);
    Wb.ow4 = repack(Pb.ow4, 432, 64, 9);
    Wb.bw1 = repack(Pb.bw1, 64, 128, 9);
    Wb.bw2 = repack(Pb.bw2, 64, 64, 9);
    Wf.dw = repack(Pf.dw, 64, 128, 9);
    Wf.ow1 = repack(Pf.ow1, 64, 192, 9);
    Wf.ow2 = repack(Pf.ow2, 64, 64, 9);
    Wf.ow3 = repack(Pf.ow3, 64, 64, 9);
    Wf.ow4 = repack(Pf.ow4, 432, 64, 9);
    Wf.bw1 = repack(Pf.bw1, 64, 192, 9);
    Wf.bw2 = repack(Pf.bw2, 64, 64, 9);
    float* Wfus = repack(fus_w, 64, 128, 1);

    {
        dim3 rg(972, 15);  // 972*256 covers the largest job (432*64*9)
        repack_all_k<<<rg, 256, 0, stream>>>(jobs);
    }

    // conv launcher: compacts null sources, pairs each with its weight slice.
    auto conv = [&](const float* a, const float* b, const float* c2,
                    const float* wp, const float* bias, int cout, int act,
                    const float* addsrc, float* out) {
        const float* srcs[3] = {a, b, c2};
        const float* S[3] = {nullptr, nullptr, nullptr};
        const float* W[3] = {nullptr, nullptr, nullptr};
        int ns = 0;
        for (int j = 0; j < 3; ++j)
            if (srcs[j]) {
                S[ns] = srcs[j];
                W[ns] = wp + (size_t)(64 * j * 9) * cout;
                ++ns;
            }
        if (cout == 432) {
            dim3 grid(3, 12, 27);
            conv3x3_k<16, 432><<<grid, 256, 0, stream>>>(
                S[0], S[1], S[2], W[0], W[1], W[2], bias, addsrc, out, ns, act);
        } else {
            dim3 grid(3, 12, 16);
            conv3x3_k<4, 64><<<grid, 256, 0, stream>>>(
                S[0], S[1], S[2], W[0], W[1], W[2], bias, addsrc, out, ns, act);
        }
    };

    for (int dir = 0; dir < 2; ++dir) {  // 0 = backward, 1 = forward
        const DirP& P = dir ? Pf : Pb;
        const DirW& Wd = dir ? Wf : Wb;
        float* feat = dir ? featF : featB;
        const float* prev1 = nullptr;
        const float* prev2 = nullptr;
        for (int i = 0; i < 8; ++i) {
            int idx = dir ? i : 7 - i;
            const float* cur = x + (size_t)idx * FRAME;
            const float* prop = prev1;
            if (i > 0) {
                // cond = [prop, cur, feat_n2] -> offset/mask net
                conv(prop, cur, prev2, Wd.ow1, P.ob1, 64, 1, nullptr, hA);
                conv(hA, nullptr, nullptr, Wd.ow2, P.ob2, 64, 1, nullptr, hB);
                conv(hB, nullptr, nullptr, Wd.ow3, P.ob3, 64, 1, nullptr, hA);
                conv(hA, nullptr, nullptr, Wd.ow4, P.ob4, 432, 0, nullptr,
                     b432);
                binit_k<<<2304, 256, 0, stream>>>(P.db, Dbuf);
                int ng = (prev2 != nullptr) ? 16 : 8;
                dim3 dg(3, 12, ng);
                dconv_split_k<<<dg, 256, 0, stream>>>(prop, prev2, b432, Wd.dw,
                                                      Dbuf);
                prop = Dbuf;
            }
            float* dst = feat + (size_t)idx * FRAME;
            if (dir == 0) {
                conv(cur, prop, nullptr, Wd.bw1, P.bb1, 64, 1, nullptr, hB);
            } else {
                conv(cur, featB + (size_t)idx * FRAME, prop, Wd.bw1, P.bb1, 64,
                     1, nullptr, hB);
            }
            conv(hB, nullptr, nullptr, Wd.bw2, P.bb2, 64, 0, prop, dst);
            prev2 = prev1;
            prev1 = dst;
        }
    }

    dim3 fg(3, 12, 64);
    fuse_k<<<fg, 256, 0, stream>>>(featB, featF, x, Wfus, fus_b,
                                   (float*)d_out);
}

// Round 4
// 5467.397 us; speedup vs baseline: 2.4242x; 1.2651x over previous
//
#include <hip/hip_runtime.h>
#include <cstddef>

#define HW96 9216
#define FRAME (64 * 9216)

typedef unsigned short ushort_t;
typedef __attribute__((ext_vector_type(8))) short bf16x8;
typedef __attribute__((ext_vector_type(16))) float f32x16;

// packed u32 = (bf16 hi bits << 16) | bf16 lo bits; value = hi + lo exactly
__device__ __forceinline__ float unpk(unsigned p) {
    return __uint_as_float(p & 0xFFFF0000u) + __uint_as_float(p << 16);
}
__device__ __forceinline__ unsigned pk(float v) {
    unsigned u = __float_as_uint(v);
    unsigned hi = u & 0xFFFF0000u;
    float rem = v - __uint_as_float(hi);
    unsigned r = __float_as_uint(rem);
    unsigned lo = (r + 0x7FFFu + ((r >> 16) & 1u)) >> 16;
    return hi | (lo & 0xFFFFu);
}

// ---------------------------------------------------------------------------
// Plain repack: OIHW -> [i][tap][o] fp32 (dconv weights + fusion 1x1).
// ---------------------------------------------------------------------------
struct RepackJob { const float* src; float* dst; int O, I, T; };
struct RepackJobs { RepackJob j[3]; };

__global__ __launch_bounds__(256) void repack_all_k(RepackJobs jobs) {
    const RepackJob& J = jobs.j[blockIdx.y];
    int idx = blockIdx.x * 256 + threadIdx.x;
    int total = J.O * J.I * J.T;
    if (idx >= total) return;
    int o = idx % J.O;
    int it = idx / J.O;
    int t = it % J.T;
    int i = it / J.T;
    J.dst[idx] = J.src[(o * J.I + i) * J.T + t];
}

// ---------------------------------------------------------------------------
// MFMA A-fragment prepack with bf16 hi/lo split.
// Layout: [hl][t][cc][mt][lane(64)][j(8)] ushort; hl offset = total.
// A[m=lane&31][k=(lane>>5)*8+j], m = mt*32+(lane&31), cin = cc*16+k.
// ---------------------------------------------------------------------------
struct FragJob { const float* src; ushort_t* dst; int O, I, MT, KC; };
struct FragJobs { FragJob j[12]; };

__global__ __launch_bounds__(256) void frag_all_k(FragJobs jobs) {
    const FragJob& J = jobs.j[blockIdx.y];
    int idx = blockIdx.x * 256 + threadIdx.x;
    int total = 9 * J.KC * J.MT * 512;
    if (idx >= total) return;
    int jj = idx & 7;
    int lane = (idx >> 3) & 63;
    int rem = idx >> 9;  // (t*KC + cc)*MT + mt
    int mt = rem % J.MT;
    rem /= J.MT;
    int cc = rem % J.KC;
    int t = rem / J.KC;
    int o = mt * 32 + (lane & 31);
    int ci = cc * 16 + (lane >> 5) * 8 + jj;
    float wv = (o < J.O && ci < J.I) ? J.src[(o * J.I + ci) * 9 + t] : 0.f;
    unsigned u = __float_as_uint(wv);
    float remf = wv - __uint_as_float(u & 0xFFFF0000u);
    unsigned rr = __float_as_uint(remf);
    ushort_t lo = (ushort_t)((rr + 0x7FFFu + ((rr >> 16) & 1u)) >> 16);
    J.dst[idx] = (ushort_t)(u >> 16);
    J.dst[total + idx] = lo;
}

// ---------------------------------------------------------------------------
// pack fp32 plane(s) -> packed u32
// ---------------------------------------------------------------------------
__global__ __launch_bounds__(256) void pack_k(const float* __restrict__ src,
                                              unsigned* __restrict__ dst,
                                              int n) {
    int i = blockIdx.x * 256 + threadIdx.x;
    if (i < n) dst[i] = pk(src[i]);
}

// ---------------------------------------------------------------------------
// MFMA implicit-GEMM 3x3 conv. Block: 128 thr (2 waves), tile M=64 x N=32
// (one pixel row of 32). K = cin*9 via chunks of 16 cin. 3-term bf16 split.
// Sources: up to 3 packed-u32 planes of 64 ch (compacted, ccN = orig chunk
// base). LDS: hi/lo image tile [3 rows][34 cols][16 c, pad 24].
// ---------------------------------------------------------------------------
__global__ __launch_bounds__(128) void convm_k(
    const unsigned* __restrict__ s0, const unsigned* __restrict__ s1,
    const unsigned* __restrict__ s2, const ushort_t* __restrict__ wfrag,
    int KCfull, int MT, int cc0, int cc1, int cc2, int nsrc,
    const float* __restrict__ bias, int Creal,
    const float* __restrict__ addsrc, unsigned* __restrict__ outpk, int act) {
    const int tid = threadIdx.x;
    const int lane = tid & 63;
    const int wv = tid >> 6;  // wave 0..1 -> mtile half
    const int x0 = blockIdx.x * 32;
    const int y0 = blockIdx.y;
    const int mt = blockIdx.z * 2 + wv;
    const int ln31 = lane & 31;
    const int half = lane >> 5;

    __shared__ __align__(16) ushort_t ldsHi[3 * 34 * 24];
    __shared__ __align__(16) ushort_t ldsLo[3 * 34 * 24];

    // staging decode, loop-invariant: 1632 elems = 16 c x (3 rows x 34 cols)
    int goff[13], lidx[13];
#pragma unroll
    for (int i = 0; i < 13; ++i) {
        int e = tid + i * 128;
        int ci = e / 102;
        int rem = e - ci * 102;
        int r = rem / 34;
        int col = rem - r * 34;
        int gy = y0 - 1 + r, gx = x0 - 1 + col;
        bool in = (e < 1632);
        bool ok = in && ((unsigned)gy < 96u) && ((unsigned)gx < 96u);
        goff[i] = ok ? (ci * HW96 + gy * 96 + gx) : -1;
        lidx[i] = in ? ((r * 34 + col) * 24 + ci) : -1;
    }

    f32x16 acc;
#pragma unroll
    for (int r = 0; r < 16; ++r) acc[r] = 0.f;

    const size_t hlOff = (size_t)9 * KCfull * MT * 512;
    const int nch = 4 * nsrc;
    for (int cc = 0; cc < nch; ++cc) {
        int j = cc >> 2;
        const unsigned* src = (j == 0) ? s0 : (j == 1 ? s1 : s2);
        const unsigned* sp = src + (cc & 3) * 16 * HW96;
        int ccorig = ((j == 0) ? cc0 : (j == 1 ? cc1 : cc2)) + (cc & 3);
        __syncthreads();
#pragma unroll
        for (int i = 0; i < 13; ++i) {
            if (lidx[i] >= 0) {
                unsigned p = (goff[i] >= 0) ? sp[goff[i]] : 0u;
                ldsHi[lidx[i]] = (ushort_t)(p >> 16);
                ldsLo[lidx[i]] = (ushort_t)(p & 0xFFFFu);
            }
        }
        __syncthreads();
#pragma unroll
        for (int t = 0; t < 9; ++t) {
            const int ky = t / 3, kx = t % 3;
            const ushort_t* ab =
                wfrag + ((size_t)((t * KCfull + ccorig) * MT + mt) * 64 + lane) * 8;
            bf16x8 Ah = *(const bf16x8*)ab;
            bf16x8 Al = *(const bf16x8*)(ab + hlOff);
            int lb = (ky * 34 + ln31 + kx) * 24 + half * 8;
            bf16x8 Bh = *(const bf16x8*)(ldsHi + lb);
            bf16x8 Bl = *(const bf16x8*)(ldsLo + lb);
            acc = __builtin_amdgcn_mfma_f32_32x32x16_bf16(Ah, Bh, acc, 0, 0, 0);
            acc = __builtin_amdgcn_mfma_f32_32x32x16_bf16(Al, Bh, acc, 0, 0, 0);
            acc = __builtin_amdgcn_mfma_f32_32x32x16_bf16(Ah, Bl, acc, 0, 0, 0);
        }
    }

    // epilogue: C/D layout col=lane&31 (pixel), row=(r&3)+8*(r>>2)+4*half
    const int px = y0 * 96 + x0 + ln31;
#pragma unroll
    for (int r = 0; r < 16; ++r) {
        int m = (r & 3) + 8 * (r >> 2) + 4 * half;
        int cout = mt * 32 + m;
        if (cout < Creal) {
            float v = acc[r] + bias[cout];
            if (act) v = (v >= 0.f) ? v : 0.1f * v;
            if (addsrc) v += addsrc[(size_t)cout * HW96 + px];
            outpk[(size_t)cout * HW96 + px] = pk(v);
        }
    }
}

// ---------------------------------------------------------------------------
// out[ch][pix] = bias[ch] (pre-init for dconv atomic accumulation)
// ---------------------------------------------------------------------------
__global__ __launch_bounds__(256) void binit_k(const float* __restrict__ bias,
                                               float* __restrict__ out) {
    int i = blockIdx.x * 256 + threadIdx.x;
    out[i] = bias[i / HW96];
}

// ---------------------------------------------------------------------------
// Modulated deformable conv v2, split-G (one group per block-z), packed-u32
// feature/raw planes, fp32 atomic output.
// ---------------------------------------------------------------------------
__global__ __launch_bounds__(256) void dconv_split_k(
    const unsigned* __restrict__ sA, const unsigned* __restrict__ sB,
    const unsigned* __restrict__ raw, const float* __restrict__ wdp,
    float* __restrict__ out) {
    const int tx = threadIdx.x & 31;
    const int ty = threadIdx.x >> 5;
    const int px = blockIdx.x * 32 + tx;
    const int py = blockIdx.y * 8 + ty;
    const int pidx = py * 96 + px;
    const int g = blockIdx.z;
    const unsigned* src = (g < 8) ? sA : sB;
    const int cb = (g & 7) * 8;

    float acc[64];
#pragma unroll
    for (int o = 0; o < 64; ++o) acc[o] = 0.f;

#pragma unroll
    for (int k = 0; k < 9; ++k) {
        const int ky = k / 3, kx = k % 3;
        float ry = unpk(raw[(size_t)(g * 18 + k * 2 + 0) * HW96 + pidx]);
        float rx = unpk(raw[(size_t)(g * 18 + k * 2 + 1) * HW96 + pidx]);
        float rm = unpk(raw[(size_t)(288 + g * 9 + k) * HW96 + pidx]);
        float oy = 5.f * (1.f - 2.f / (1.f + __expf(2.f * ry)));
        float ox = 5.f * (1.f - 2.f / (1.f + __expf(2.f * rx)));
        float m = 1.f / (1.f + __expf(-rm));
        float sy = oy + (float)(py - 1 + ky);
        float sx = ox + (float)(px - 1 + kx);
        float fy0 = floorf(sy), fx0 = floorf(sx);
        float fy = sy - fy0, fx = sx - fx0;
        int y0 = (int)fy0, x0 = (int)fx0;
        int y1 = y0 + 1, x1 = x0 + 1;
        bool vy0 = (unsigned)y0 < 96u, vy1 = (unsigned)y1 < 96u;
        bool vx0 = (unsigned)x0 < 96u, vx1 = (unsigned)x1 < 96u;
        int cy0 = min(max(y0, 0), 95), cy1 = min(max(y1, 0), 95);
        int cx0 = min(max(x0, 0), 95), cx1 = min(max(x1, 0), 95);
        float w00 = (1.f - fy) * (1.f - fx) * ((vy0 && vx0) ? 1.f : 0.f);
        float w01 = (1.f - fy) * fx * ((vy0 && vx1) ? 1.f : 0.f);
        float w10 = fy * (1.f - fx) * ((vy1 && vx0) ? 1.f : 0.f);
        float w11 = fy * fx * ((vy1 && vx1) ? 1.f : 0.f);
        int i00 = cy0 * 96 + cx0, i01 = cy0 * 96 + cx1;
        int i10 = cy1 * 96 + cx0, i11 = cy1 * 96 + cx1;
#pragma unroll
        for (int c = 0; c < 8; ++c) {
            const unsigned* plane = src + (size_t)(cb + c) * HW96;
            float v = w00 * unpk(plane[i00]) + w01 * unpk(plane[i01]) +
                      w10 * unpk(plane[i10]) + w11 * unpk(plane[i11]);
            float col = v * m;
            const float* wc = wdp + (size_t)((g * 8 + c) * 9 + k) * 64;
#pragma unroll
            for (int o = 0; o < 64; ++o) acc[o] = fmaf(wc[o], col, acc[o]);
        }
    }
#pragma unroll
    for (int o = 0; o < 64; ++o)
        unsafeAtomicAdd(&out[(size_t)o * HW96 + pidx], acc[o]);
}

// ---------------------------------------------------------------------------
// Fusion: 1x1 conv over [featB[t], featF[t]] (packed) + bias + x, fp32 out.
// ---------------------------------------------------------------------------
__global__ __launch_bounds__(256) void fuse_k(
    const unsigned* __restrict__ featB, const unsigned* __restrict__ featF,
    const float* __restrict__ x, const float* __restrict__ wp,
    const float* __restrict__ bias, float* __restrict__ out) {
    const int tx = threadIdx.x & 31;
    const int ty = threadIdx.x >> 5;
    const int px = blockIdx.x * 32 + tx;
    const int py = blockIdx.y * 8 + ty;
    const int t = blockIdx.z >> 3;
    const int obase = (blockIdx.z & 7) * 8;
    const int pidx = py * 96 + px;
    const unsigned* fB = featB + (size_t)t * FRAME;
    const unsigned* fF = featF + (size_t)t * FRAME;

    float acc[8];
#pragma unroll
    for (int o = 0; o < 8; ++o) acc[o] = 0.f;

    for (int i = 0; i < 64; ++i) {
        float v = unpk(fB[(size_t)i * HW96 + pidx]);
        const float* wr = wp + i * 64 + obase;
#pragma unroll
        for (int o = 0; o < 8; ++o) acc[o] = fmaf(wr[o], v, acc[o]);
    }
    for (int i = 0; i < 64; ++i) {
        float v = unpk(fF[(size_t)i * HW96 + pidx]);
        const float* wr = wp + (64 + i) * 64 + obase;
#pragma unroll
        for (int o = 0; o < 8; ++o) acc[o] = fmaf(wr[o], v, acc[o]);
    }
    const float* xt = x + (size_t)t * FRAME;
#pragma unroll
    for (int o = 0; o < 8; ++o)
        out[(size_t)t * FRAME + (size_t)(obase + o) * HW96 + pidx] =
            acc[o] + bias[obase + o] + xt[(size_t)(obase + o) * HW96 + pidx];
}

// ---------------------------------------------------------------------------
extern "C" void kernel_launch(void* const* d_in, const int* in_sizes, int n_in,
                              void* d_out, int out_size, void* d_ws,
                              size_t ws_size, hipStream_t stream) {
    const float* x = (const float*)d_in[0];
    auto gp = [&](int i) { return (const float*)d_in[i]; };

    struct DirP {
        const float *dw, *db, *ow1, *ob1, *ow2, *ob2, *ow3, *ob3, *ow4, *ob4,
            *bw1, *bb1, *bw2, *bb2;
    };
    DirP Pb{gp(1), gp(2), gp(3), gp(4), gp(5), gp(6), gp(7),
            gp(8), gp(9), gp(10), gp(11), gp(12), gp(13), gp(14)};
    DirP Pf{gp(15), gp(16), gp(17), gp(18), gp(19), gp(20), gp(21),
            gp(22), gp(23), gp(24), gp(25), gp(26), gp(27), gp(28)};
    const float* fus_w = gp(29);
    const float* fus_b = gp(30);

    // ---- workspace carve-up (4-byte units) ----
    unsigned* featBpk = (unsigned*)d_ws;
    unsigned* featFpk = featBpk + (size_t)8 * FRAME;
    unsigned* xpk = featFpk + (size_t)8 * FRAME;
    float* Dbuf = (float*)(xpk + (size_t)8 * FRAME);
    unsigned* Dpk = (unsigned*)(Dbuf + FRAME);
    unsigned* hApk = Dpk + FRAME;
    unsigned* hBpk = hApk + FRAME;
    unsigned* b432pk = hBpk + FRAME;  // 448 planes
    float* wdpB = (float*)(b432pk + (size_t)448 * HW96);
    float* wdpF = wdpB + 64 * 128 * 9;
    float* wfus = wdpF + 64 * 128 * 9;
    ushort_t* fragp = (ushort_t*)(wfus + 128 * 64);

    auto falloc = [&](int KC, int MT) {
        ushort_t* p = fragp;
        fragp += (size_t)2 * 9 * KC * MT * 512;
        return p;
    };

    // ---- weight prep (fp32 repacks + MFMA fragments) ----
    RepackJobs rj;
    rj.j[0] = RepackJob{Pb.dw, wdpB, 64, 128, 9};
    rj.j[1] = RepackJob{Pf.dw, wdpF, 64, 128, 9};
    rj.j[2] = RepackJob{fus_w, wfus, 64, 128, 1};
    repack_all_k<<<dim3(288, 3), 256, 0, stream>>>(rj);

    struct DirW { ushort_t *ow1, *ow2, *ow3, *ow4, *bw1, *bw2; int bw1KC; };
    FragJobs fj;
    int nf = 0;
    auto fjob = [&](const float* src, int O, int I, int MT, int KC) {
        ushort_t* dst = falloc(KC, MT);
        fj.j[nf++] = FragJob{src, dst, O, I, MT, KC};
        return dst;
    };
    DirW Wb, Wf;
    Wb.ow1 = fjob(Pb.ow1, 64, 192, 2, 12);
    Wb.ow2 = fjob(Pb.ow2, 64, 64, 2, 4);
    Wb.ow3 = fjob(Pb.ow3, 64, 64, 2, 4);
    Wb.ow4 = fjob(Pb.ow4, 432, 64, 14, 4);
    Wb.bw1 = fjob(Pb.bw1, 64, 128, 2, 8);
    Wb.bw1KC = 8;
    Wb.bw2 = fjob(Pb.bw2, 64, 64, 2, 4);
    Wf.ow1 = fjob(Pf.ow1, 64, 192, 2, 12);
    Wf.ow2 = fjob(Pf.ow2, 64, 64, 2, 4);
    Wf.ow3 = fjob(Pf.ow3, 64, 64, 2, 4);
    Wf.ow4 = fjob(Pf.ow4, 432, 64, 14, 4);
    Wf.bw1 = fjob(Pf.bw1, 64, 192, 2, 12);
    Wf.bw1KC = 12;
    Wf.bw2 = fjob(Pf.bw2, 64, 64, 2, 4);
    frag_all_k<<<dim3(2016, 12), 256, 0, stream>>>(fj);

    // pack input frames
    pack_k<<<(8 * FRAME + 255) / 256, 256, 0, stream>>>(x, xpk, 8 * FRAME);

    // convm launcher with source compaction
    auto convm = [&](const unsigned* a, const unsigned* b, const unsigned* c2,
                     const ushort_t* frag, int KCfull, int MT,
                     const float* bias, int Creal, const float* addsrc,
                     unsigned* out, int act) {
        const unsigned* srcs[3] = {a, b, c2};
        const unsigned* S[3] = {nullptr, nullptr, nullptr};
        int P[3] = {0, 0, 0};
        int ns = 0;
        for (int j = 0; j < 3; ++j)
            if (srcs[j]) {
                S[ns] = srcs[j];
                P[ns] = j * 4;
                ++ns;
            }
        dim3 g(3, 96, MT / 2);
        convm_k<<<g, 128, 0, stream>>>(S[0], S[1], S[2], frag, KCfull, MT,
                                       P[0], P[1], P[2], ns, bias, Creal,
                                       addsrc, out, act);
    };

    for (int dir = 0; dir < 2; ++dir) {  // 0 = backward, 1 = forward
        const DirP& P = dir ? Pf : Pb;
        const DirW& W = dir ? Wf : Wb;
        float* wdp = dir ? wdpF : wdpB;
        unsigned* feat = dir ? featFpk : featBpk;
        const unsigned* prev1 = nullptr;
        const unsigned* prev2 = nullptr;
        for (int i = 0; i < 8; ++i) {
            int idx = dir ? i : 7 - i;
            const unsigned* cur = xpk + (size_t)idx * FRAME;
            const unsigned* prop = prev1;
            const float* propf = nullptr;  // fp32 addsrc for bw2
            if (i > 0) {
                convm(prop, cur, prev2, W.ow1, 12, 2, P.ob1, 64, nullptr, hApk, 1);
                convm(hApk, nullptr, nullptr, W.ow2, 4, 2, P.ob2, 64, nullptr, hBpk, 1);
                convm(hBpk, nullptr, nullptr, W.ow3, 4, 2, P.ob3, 64, nullptr, hApk, 1);
                convm(hApk, nullptr, nullptr, W.ow4, 4, 14, P.ob4, 432, nullptr, b432pk, 0);
                binit_k<<<2304, 256, 0, stream>>>(P.db, Dbuf);
                int ng = (prev2 != nullptr) ? 16 : 8;
                dconv_split_k<<<dim3(3, 12, ng), 256, 0, stream>>>(
                    prop, prev2, b432pk, wdp, Dbuf);
                pack_k<<<(FRAME + 255) / 256, 256, 0, stream>>>(Dbuf, Dpk, FRAME);
                prop = Dpk;
                propf = Dbuf;
            }
            unsigned* dst = feat + (size_t)idx * FRAME;
            if (dir == 0) {
                convm(cur, prop, nullptr, W.bw1, W.bw1KC, 2, P.bb1, 64, nullptr, hBpk, 1);
            } else {
                convm(cur, featBpk + (size_t)idx * FRAME, prop, W.bw1, W.bw1KC,
                      2, P.bb1, 64, nullptr, hBpk, 1);
            }
            convm(hBpk, nullptr, nullptr, W.bw2, 4, 2, P.bb2, 64, propf, dst, 0);
            prev2 = prev1;
            prev1 = dst;
        }
    }

    fuse_k<<<dim3(3, 12, 64), 256, 0, stream>>>(featBpk, featFpk, x, wfus,
                                                fus_b, (float*)d_out);
}

// Round 5
// 3793.808 us; speedup vs baseline: 3.4936x; 1.4411x over previous
//
#include <hip/hip_runtime.h>
#include <cstddef>

#define HW96 9216
#define FRAME (64 * 9216)

typedef unsigned short ushort_t;
typedef __attribute__((ext_vector_type(8))) short bf16x8;
typedef __attribute__((ext_vector_type(4))) float f32x4;

// packed u32 = (bf16 hi bits << 16) | bf16 lo bits; value = hi + lo exactly
__device__ __forceinline__ float unpk(unsigned p) {
    return __uint_as_float(p & 0xFFFF0000u) + __uint_as_float(p << 16);
}
__device__ __forceinline__ unsigned pk(float v) {
    unsigned u = __float_as_uint(v);
    unsigned hi = u & 0xFFFF0000u;
    float rem = v - __uint_as_float(hi);
    unsigned r = __float_as_uint(rem);
    unsigned lo = (r + 0x7FFFu + ((r >> 16) & 1u)) >> 16;
    return hi | (lo & 0xFFFFu);
}

// ---------------------------------------------------------------------------
// Plain repack: OIHW -> [i][tap][o] fp32 (dconv weights + fusion 1x1).
// ---------------------------------------------------------------------------
struct RepackJob { const float* src; float* dst; int O, I, T; };
struct RepackJobs { RepackJob j[3]; };

__global__ __launch_bounds__(256) void repack_all_k(RepackJobs jobs) {
    const RepackJob& J = jobs.j[blockIdx.y];
    int idx = blockIdx.x * 256 + threadIdx.x;
    int total = J.O * J.I * J.T;
    if (idx >= total) return;
    int o = idx % J.O;
    int it = idx / J.O;
    int t = it % J.T;
    int i = it / J.T;
    J.dst[idx] = J.src[(o * J.I + i) * J.T + t];
}

// ---------------------------------------------------------------------------
// MFMA A-fragment prepack (16x16x32) with bf16 hi/lo split.
// Layout: [hl][t][cc][ot][lane(64)][j(8)]; hl offset = total.
// A[m=lane&15][k=(lane>>4)*8+j]; o = ot*16+m, cin = cc*32+k.
// ---------------------------------------------------------------------------
struct FragJob { const float* src; ushort_t* dst; int O, I, OT, KC; };
struct FragJobs { FragJob j[12]; };

__global__ __launch_bounds__(256) void frag_all_k(FragJobs jobs) {
    const FragJob& J = jobs.j[blockIdx.y];
    int idx = blockIdx.x * 256 + threadIdx.x;
    int total = 9 * J.KC * J.OT * 512;
    if (idx >= total) return;
    int jj = idx & 7;
    int lane = (idx >> 3) & 63;
    int rem = idx >> 9;  // (t*KC + cc)*OT + ot
    int ot = rem % J.OT;
    rem /= J.OT;
    int cc = rem % J.KC;
    int t = rem / J.KC;
    int o = ot * 16 + (lane & 15);
    int ci = cc * 32 + (lane >> 4) * 8 + jj;
    float wv = (o < J.O && ci < J.I) ? J.src[(o * J.I + ci) * 9 + t] : 0.f;
    unsigned u = __float_as_uint(wv);
    float remf = wv - __uint_as_float(u & 0xFFFF0000u);
    unsigned rr = __float_as_uint(remf);
    ushort_t lo = (ushort_t)((rr + 0x7FFFu + ((rr >> 16) & 1u)) >> 16);
    J.dst[idx] = (ushort_t)(u >> 16);
    J.dst[total + idx] = lo;
}

// ---------------------------------------------------------------------------
// pack fp32 plane(s) -> packed u32
// ---------------------------------------------------------------------------
__global__ __launch_bounds__(256) void pack_k(const float* __restrict__ src,
                                              unsigned* __restrict__ dst,
                                              int n) {
    int i = blockIdx.x * 256 + threadIdx.x;
    if (i < n) dst[i] = pk(src[i]);
}

// ---------------------------------------------------------------------------
// MFMA implicit-GEMM 3x3 conv, 16x16x32 bf16, 3-term hi/lo split.
// Block: 256 thr = 4 waves; wave tile = 16 out x 16 px (one row segment).
// Per 64-ch source: stage 3x18x64 hi/lo window in LDS (cin padded to 72),
// then 9 taps x 2 cin-chunks x 3 MFMAs per wave. Sources may be packed-u32
// or fp32 (packed on the fly).
// ---------------------------------------------------------------------------
__global__ __launch_bounds__(256) void convm_k(
    const void* __restrict__ s0, const void* __restrict__ s1,
    const void* __restrict__ s2, int b0, int b1, int b2, int f32mask,
    int nsrc, const ushort_t* __restrict__ wfrag, int KCfull, int OTtot,
    const float* __restrict__ bias, int Creal,
    const float* __restrict__ addsrc, unsigned* __restrict__ outpk, int act) {
    const int tid = threadIdx.x;
    const int lane = tid & 63;
    const int w = tid >> 6;
    const int xb = (blockIdx.x % 6) * 16;
    const int y = blockIdx.x / 6;
    const int ot = blockIdx.y * 4 + w;
    const int n = lane & 15;
    const int quad = lane >> 4;

    __shared__ __align__(16) ushort_t ldsH[3 * 18 * 72];
    __shared__ __align__(16) ushort_t ldsL[3 * 18 * 72];

    f32x4 acc0, acc1;
#pragma unroll
    for (int r = 0; r < 4; ++r) { acc0[r] = 0.f; acc1[r] = 0.f; }

    const size_t hlOff = (size_t)9 * KCfull * OTtot * 512;

    for (int j = 0; j < nsrc; ++j) {
        const void* sv = (j == 0) ? s0 : (j == 1 ? s1 : s2);
        const int base = (j == 0) ? b0 : (j == 1 ? b1 : b2);
        const bool isf = (f32mask >> j) & 1;
        __syncthreads();
#pragma unroll
        for (int i = 0; i < 14; ++i) {
            int e = tid + i * 256;
            if (e < 3456) {
                int ci = e / 54;
                int rem = e - ci * 54;
                int r = rem / 18;
                int col = rem - r * 18;
                int gy = y - 1 + r, gx = xb - 1 + col;
                unsigned p = 0;
                if ((unsigned)gy < 96u && (unsigned)gx < 96u) {
                    int off = ci * HW96 + gy * 96 + gx;
                    p = isf ? pk(((const float*)sv)[off])
                            : ((const unsigned*)sv)[off];
                }
                int la = (r * 18 + col) * 72 + ci;
                ldsH[la] = (ushort_t)(p >> 16);
                ldsL[la] = (ushort_t)(p & 0xFFFFu);
            }
        }
        __syncthreads();
#pragma unroll
        for (int t = 0; t < 9; ++t) {
            const int ky = t / 3, kx = t % 3;
#pragma unroll
            for (int cc2 = 0; cc2 < 2; ++cc2) {
                const int ccor = base + cc2;
                const ushort_t* ab =
                    wfrag +
                    (((size_t)(t * KCfull + ccor) * OTtot + ot) * 64 + lane) * 8;
                bf16x8 Ah = *(const bf16x8*)ab;
                bf16x8 Al = *(const bf16x8*)(ab + hlOff);
                int lb = (ky * 18 + n + kx) * 72 + cc2 * 32 + quad * 8;
                bf16x8 Bh = *(const bf16x8*)(ldsH + lb);
                bf16x8 Bl = *(const bf16x8*)(ldsL + lb);
                if (t & 1) {
                    acc1 = __builtin_amdgcn_mfma_f32_16x16x32_bf16(Ah, Bh, acc1, 0, 0, 0);
                    acc1 = __builtin_amdgcn_mfma_f32_16x16x32_bf16(Al, Bh, acc1, 0, 0, 0);
                    acc1 = __builtin_amdgcn_mfma_f32_16x16x32_bf16(Ah, Bl, acc1, 0, 0, 0);
                } else {
                    acc0 = __builtin_amdgcn_mfma_f32_16x16x32_bf16(Ah, Bh, acc0, 0, 0, 0);
                    acc0 = __builtin_amdgcn_mfma_f32_16x16x32_bf16(Al, Bh, acc0, 0, 0, 0);
                    acc0 = __builtin_amdgcn_mfma_f32_16x16x32_bf16(Ah, Bl, acc0, 0, 0, 0);
                }
            }
        }
    }

    // epilogue: C/D col = lane&15 (px), row = quad*4 + r (out within otile)
    const int px = y * 96 + xb + n;
#pragma unroll
    for (int r = 0; r < 4; ++r) {
        int cout = ot * 16 + quad * 4 + r;
        if (cout < Creal) {
            float v = acc0[r] + acc1[r] + bias[cout];
            if (act) v = (v >= 0.f) ? v : 0.1f * v;
            if (addsrc) v += addsrc[(size_t)cout * HW96 + px];
            outpk[(size_t)cout * HW96 + px] = pk(v);
        }
    }
}

// ---------------------------------------------------------------------------
// out[ch][pix] = bias[ch] (pre-init for dconv atomic accumulation)
// ---------------------------------------------------------------------------
__global__ __launch_bounds__(256) void binit_k(const float* __restrict__ bias,
                                               float* __restrict__ out) {
    int i = blockIdx.x * 256 + threadIdx.x;
    out[i] = bias[i / HW96];
}

// ---------------------------------------------------------------------------
// Modulated deformable conv v2, split-G (one group per block-z), packed-u32
// planes, fp32 atomic output. Raw tap words preloaded (27 independent loads).
// ---------------------------------------------------------------------------
__global__ __launch_bounds__(256) void dconv_split_k(
    const unsigned* __restrict__ sA, const unsigned* __restrict__ sB,
    const unsigned* __restrict__ raw, const float* __restrict__ wdp,
    float* __restrict__ out) {
    const int tx = threadIdx.x & 31;
    const int ty = threadIdx.x >> 5;
    const int px = blockIdx.x * 32 + tx;
    const int py = blockIdx.y * 8 + ty;
    const int pidx = py * 96 + px;
    const int g = blockIdx.z;
    const unsigned* src = (g < 8) ? sA : sB;
    const int cb = (g & 7) * 8;

    unsigned rw[27];
#pragma unroll
    for (int kk = 0; kk < 9; ++kk) {
        rw[kk] = raw[(size_t)(g * 18 + kk * 2 + 0) * HW96 + pidx];
        rw[9 + kk] = raw[(size_t)(g * 18 + kk * 2 + 1) * HW96 + pidx];
        rw[18 + kk] = raw[(size_t)(288 + g * 9 + kk) * HW96 + pidx];
    }

    float acc[64];
#pragma unroll
    for (int o = 0; o < 64; ++o) acc[o] = 0.f;

#pragma unroll
    for (int k = 0; k < 9; ++k) {
        const int ky = k / 3, kx = k % 3;
        float ry = unpk(rw[k]);
        float rx = unpk(rw[9 + k]);
        float rm = unpk(rw[18 + k]);
        float oy = 5.f * (1.f - 2.f / (1.f + __expf(2.f * ry)));
        float ox = 5.f * (1.f - 2.f / (1.f + __expf(2.f * rx)));
        float m = 1.f / (1.f + __expf(-rm));
        float sy = oy + (float)(py - 1 + ky);
        float sx = ox + (float)(px - 1 + kx);
        float fy0 = floorf(sy), fx0 = floorf(sx);
        float fy = sy - fy0, fx = sx - fx0;
        int y0 = (int)fy0, x0 = (int)fx0;
        int y1 = y0 + 1, x1 = x0 + 1;
        bool vy0 = (unsigned)y0 < 96u, vy1 = (unsigned)y1 < 96u;
        bool vx0 = (unsigned)x0 < 96u, vx1 = (unsigned)x1 < 96u;
        int cy0 = min(max(y0, 0), 95), cy1 = min(max(y1, 0), 95);
        int cx0 = min(max(x0, 0), 95), cx1 = min(max(x1, 0), 95);
        float w00 = (1.f - fy) * (1.f - fx) * ((vy0 && vx0) ? 1.f : 0.f);
        float w01 = (1.f - fy) * fx * ((vy0 && vx1) ? 1.f : 0.f);
        float w10 = fy * (1.f - fx) * ((vy1 && vx0) ? 1.f : 0.f);
        float w11 = fy * fx * ((vy1 && vx1) ? 1.f : 0.f);
        int i00 = cy0 * 96 + cx0, i01 = cy0 * 96 + cx1;
        int i10 = cy1 * 96 + cx0, i11 = cy1 * 96 + cx1;
#pragma unroll
        for (int c = 0; c < 8; ++c) {
            const unsigned* plane = src + (size_t)(cb + c) * HW96;
            float v = w00 * unpk(plane[i00]) + w01 * unpk(plane[i01]) +
                      w10 * unpk(plane[i10]) + w11 * unpk(plane[i11]);
            float col = v * m;
            const float* wc = wdp + (size_t)((g * 8 + c) * 9 + k) * 64;
#pragma unroll
            for (int o = 0; o < 64; ++o) acc[o] = fmaf(wc[o], col, acc[o]);
        }
    }
#pragma unroll
    for (int o = 0; o < 64; ++o)
        unsafeAtomicAdd(&out[(size_t)o * HW96 + pidx], acc[o]);
}

// ---------------------------------------------------------------------------
// Fusion: 1x1 conv over [featB[t], featF[t]] (packed) + bias + x, fp32 out.
// ---------------------------------------------------------------------------
__global__ __launch_bounds__(256) void fuse_k(
    const unsigned* __restrict__ featB, const unsigned* __restrict__ featF,
    const float* __restrict__ x, const float* __restrict__ wp,
    const float* __restrict__ bias, float* __restrict__ out) {
    const int tx = threadIdx.x & 31;
    const int ty = threadIdx.x >> 5;
    const int px = blockIdx.x * 32 + tx;
    const int py = blockIdx.y * 8 + ty;
    const int t = blockIdx.z >> 3;
    const int obase = (blockIdx.z & 7) * 8;
    const int pidx = py * 96 + px;
    const unsigned* fB = featB + (size_t)t * FRAME;
    const unsigned* fF = featF + (size_t)t * FRAME;

    float acc[8];
#pragma unroll
    for (int o = 0; o < 8; ++o) acc[o] = 0.f;

    for (int i = 0; i < 64; ++i) {
        float v = unpk(fB[(size_t)i * HW96 + pidx]);
        const float* wr = wp + i * 64 + obase;
#pragma unroll
        for (int o = 0; o < 8; ++o) acc[o] = fmaf(wr[o], v, acc[o]);
    }
    for (int i = 0; i < 64; ++i) {
        float v = unpk(fF[(size_t)i * HW96 + pidx]);
        const float* wr = wp + (64 + i) * 64 + obase;
#pragma unroll
        for (int o = 0; o < 8; ++o) acc[o] = fmaf(wr[o], v, acc[o]);
    }
    const float* xt = x + (size_t)t * FRAME;
#pragma unroll
    for (int o = 0; o < 8; ++o)
        out[(size_t)t * FRAME + (size_t)(obase + o) * HW96 + pidx] =
            acc[o] + bias[obase + o] + xt[(size_t)(obase + o) * HW96 + pidx];
}

// ---------------------------------------------------------------------------
extern "C" void kernel_launch(void* const* d_in, const int* in_sizes, int n_in,
                              void* d_out, int out_size, void* d_ws,
                              size_t ws_size, hipStream_t stream) {
    const float* x = (const float*)d_in[0];
    auto gp = [&](int i) { return (const float*)d_in[i]; };

    struct DirP {
        const float *dw, *db, *ow1, *ob1, *ow2, *ob2, *ow3, *ob3, *ow4, *ob4,
            *bw1, *bb1, *bw2, *bb2;
    };
    DirP Pb{gp(1), gp(2), gp(3), gp(4), gp(5), gp(6), gp(7),
            gp(8), gp(9), gp(10), gp(11), gp(12), gp(13), gp(14)};
    DirP Pf{gp(15), gp(16), gp(17), gp(18), gp(19), gp(20), gp(21),
            gp(22), gp(23), gp(24), gp(25), gp(26), gp(27), gp(28)};
    const float* fus_w = gp(29);
    const float* fus_b = gp(30);

    // ---- workspace carve-up (4-byte units) ----
    unsigned* featBpk = (unsigned*)d_ws;
    unsigned* featFpk = featBpk + (size_t)8 * FRAME;
    unsigned* xpk = featFpk + (size_t)8 * FRAME;
    float* Dbuf = (float*)(xpk + (size_t)8 * FRAME);
    unsigned* hApk = (unsigned*)(Dbuf + FRAME);
    unsigned* hBpk = hApk + FRAME;
    unsigned* b432pk = hBpk + FRAME;  // 432 planes
    float* wdpB = (float*)(b432pk + (size_t)432 * HW96);
    float* wdpF = wdpB + 64 * 128 * 9;
    float* wfus = wdpF + 64 * 128 * 9;
    ushort_t* fragp = (ushort_t*)(wfus + 128 * 64);

    auto falloc = [&](int KC, int OT) {
        ushort_t* p = fragp;
        fragp += (size_t)2 * 9 * KC * OT * 512;
        return p;
    };

    // ---- weight prep ----
    RepackJobs rj;
    rj.j[0] = RepackJob{Pb.dw, wdpB, 64, 128, 9};
    rj.j[1] = RepackJob{Pf.dw, wdpF, 64, 128, 9};
    rj.j[2] = RepackJob{fus_w, wfus, 64, 128, 1};
    repack_all_k<<<dim3(288, 3), 256, 0, stream>>>(rj);

    struct DirW { ushort_t *ow1, *ow2, *ow3, *ow4, *bw1, *bw2; int bw1KC; };
    FragJobs fj;
    int nf = 0;
    auto fjob = [&](const float* src, int O, int I, int OT, int KC) {
        ushort_t* dst = falloc(KC, OT);
        fj.j[nf++] = FragJob{src, dst, O, I, OT, KC};
        return dst;
    };
    DirW Wb, Wf;
    Wb.ow1 = fjob(Pb.ow1, 64, 192, 4, 6);
    Wb.ow2 = fjob(Pb.ow2, 64, 64, 4, 2);
    Wb.ow3 = fjob(Pb.ow3, 64, 64, 4, 2);
    Wb.ow4 = fjob(Pb.ow4, 432, 64, 28, 2);
    Wb.bw1 = fjob(Pb.bw1, 64, 128, 4, 4);
    Wb.bw1KC = 4;
    Wb.bw2 = fjob(Pb.bw2, 64, 64, 4, 2);
    Wf.ow1 = fjob(Pf.ow1, 64, 192, 4, 6);
    Wf.ow2 = fjob(Pf.ow2, 64, 64, 4, 2);
    Wf.ow3 = fjob(Pf.ow3, 64, 64, 4, 2);
    Wf.ow4 = fjob(Pf.ow4, 432, 64, 28, 2);
    Wf.bw1 = fjob(Pf.bw1, 64, 192, 4, 6);
    Wf.bw1KC = 6;
    Wf.bw2 = fjob(Pf.bw2, 64, 64, 4, 2);
    frag_all_k<<<dim3(1008, 12), 256, 0, stream>>>(fj);

    pack_k<<<(8 * FRAME + 255) / 256, 256, 0, stream>>>(x, xpk, 8 * FRAME);

    // convm launcher: compact sources; base = origIdx*2 (32-cin chunks);
    // flag bit = source is fp32.
    struct Src { const void* p; int f; };
    auto convm = [&](Src a, Src b, Src c2, const ushort_t* frag, int KCfull,
                     int OT, const float* bias, int Creal,
                     const float* addsrc, unsigned* out, int act) {
        Src srcs[3] = {a, b, c2};
        const void* S[3] = {nullptr, nullptr, nullptr};
        int B[3] = {0, 0, 0};
        int mask = 0, ns = 0;
        for (int j = 0; j < 3; ++j)
            if (srcs[j].p) {
                S[ns] = srcs[j].p;
                B[ns] = j * 2;
                if (srcs[j].f) mask |= (1 << ns);
                ++ns;
            }
        dim3 g(576, OT / 4);
        convm_k<<<g, 256, 0, stream>>>(S[0], S[1], S[2], B[0], B[1], B[2],
                                       mask, ns, frag, KCfull, OT, bias,
                                       Creal, addsrc, out, act);
    };
    Src NONE{nullptr, 0};

    for (int dir = 0; dir < 2; ++dir) {  // 0 = backward, 1 = forward
        const DirP& P = dir ? Pf : Pb;
        const DirW& W = dir ? Wf : Wb;
        float* wdp = dir ? wdpF : wdpB;
        unsigned* feat = dir ? featFpk : featBpk;
        const unsigned* prev1 = nullptr;
        const unsigned* prev2 = nullptr;
        for (int i = 0; i < 8; ++i) {
            int idx = dir ? i : 7 - i;
            const unsigned* cur = xpk + (size_t)idx * FRAME;
            const float* propf = nullptr;  // fp32 dconv output
            if (i > 0) {
                convm(Src{prev1, 0}, Src{cur, 0}, Src{prev2, 0}, W.ow1, 6, 4,
                      P.ob1, 64, nullptr, hApk, 1);
                convm(Src{hApk, 0}, NONE, NONE, W.ow2, 2, 4, P.ob2, 64,
                      nullptr, hBpk, 1);
                convm(Src{hBpk, 0}, NONE, NONE, W.ow3, 2, 4, P.ob3, 64,
                      nullptr, hApk, 1);
                convm(Src{hApk, 0}, NONE, NONE, W.ow4, 2, 28, P.ob4, 432,
                      nullptr, b432pk, 0);
                binit_k<<<2304, 256, 0, stream>>>(P.db, Dbuf);
                int ng = (prev2 != nullptr) ? 16 : 8;
                dconv_split_k<<<dim3(3, 12, ng), 256, 0, stream>>>(
                    prev1, prev2, b432pk, wdp, Dbuf);
                propf = Dbuf;
            }
            unsigned* dst = feat + (size_t)idx * FRAME;
            if (dir == 0) {
                convm(Src{cur, 0}, (i > 0) ? Src{Dbuf, 1} : NONE, NONE, W.bw1,
                      W.bw1KC, 4, P.bb1, 64, nullptr, hBpk, 1);
            } else {
                convm(Src{cur, 0}, Src{featBpk + (size_t)idx * FRAME, 0},
                      (i > 0) ? Src{Dbuf, 1} : NONE, W.bw1, W.bw1KC, 4, P.bb1,
                      64, nullptr, hBpk, 1);
            }
            convm(Src{hBpk, 0}, NONE, NONE, W.bw2, 2, 4, P.bb2, 64, propf,
                  dst, 0);
            prev2 = prev1;
            prev1 = dst;
        }
    }

    fuse_k<<<dim3(3, 12, 64), 256, 0, stream>>>(featBpk, featFpk, x, wfus,
                                                fus_b, (float*)d_out);
}

// Round 6
// 2946.076 us; speedup vs baseline: 4.4989x; 1.2877x over previous
//
#include <hip/hip_runtime.h>
#include <cstddef>

#define HW96 9216
#define FRAME (64 * 9216)

typedef unsigned short ushort_t;
typedef __attribute__((ext_vector_type(8))) short bf16x8;
typedef __attribute__((ext_vector_type(4))) float f32x4;

// packed u32 = (bf16 hi bits << 16) | bf16 lo bits; value = hi + lo exactly
__device__ __forceinline__ float unpk(unsigned p) {
    return __uint_as_float(p & 0xFFFF0000u) + __uint_as_float(p << 16);
}
__device__ __forceinline__ unsigned pk(float v) {
    unsigned u = __float_as_uint(v);
    unsigned hi = u & 0xFFFF0000u;
    float rem = v - __uint_as_float(hi);
    unsigned r = __float_as_uint(rem);
    unsigned lo = (r + 0x7FFFu + ((r >> 16) & 1u)) >> 16;
    return hi | (lo & 0xFFFFu);
}
__device__ __forceinline__ void split16(float v, ushort_t& h, ushort_t& l) {
    unsigned u = __float_as_uint(v);
    h = (ushort_t)(u >> 16);
    float rem = v - __uint_as_float(u & 0xFFFF0000u);
    unsigned r = __float_as_uint(rem);
    l = (ushort_t)((r + 0x7FFFu + ((r >> 16) & 1u)) >> 16);
}

// ---------------------------------------------------------------------------
// Plain repack: OIHW -> [i][o] fp32 (fusion 1x1 only).
// ---------------------------------------------------------------------------
__global__ __launch_bounds__(256) void repack_fus_k(const float* __restrict__ w,
                                                    float* __restrict__ wp) {
    int idx = blockIdx.x * 256 + threadIdx.x;  // 128*64
    if (idx >= 128 * 64) return;
    int o = idx % 64;
    int i = idx / 64;
    wp[idx] = w[o * 128 + i];
}

// ---------------------------------------------------------------------------
// MFMA A-fragment prepack (16x16x32) with bf16 hi/lo split.
// mode 0 (3x3 conv): layout [hl][t][cc][ot][lane][j]; K = cin chunks of 32.
// mode 1 (dconv):    layout [hl][cc][ot][lane][j]; K = g*72 + tap*8 + c.
// A[m=lane&15][k=(lane>>4)*8+j].
// ---------------------------------------------------------------------------
struct FragJob { const float* src; ushort_t* dst; int O, I, OT, KC, mode; };
struct FragJobs { FragJob j[14]; };

__global__ __launch_bounds__(256) void frag_all_k(FragJobs jobs) {
    const FragJob& J = jobs.j[blockIdx.y];
    int idx = blockIdx.x * 256 + threadIdx.x;
    int total = (J.mode ? 1 : 9) * J.KC * J.OT * 512;
    if (idx >= total) return;
    int jj = idx & 7;
    int lane = (idx >> 3) & 63;
    int rem = idx >> 9;
    int ot = rem % J.OT;
    rem /= J.OT;
    int cc = rem % J.KC;
    int t = rem / J.KC;
    int o = ot * 16 + (lane & 15);
    float wv = 0.f;
    if (J.mode == 0) {
        int ci = cc * 32 + (lane >> 4) * 8 + jj;
        if (o < J.O && ci < J.I) wv = J.src[(o * J.I + ci) * 9 + t];
    } else {
        int K = cc * 32 + (lane >> 4) * 8 + jj;
        int g = K / 72, r2 = K % 72;
        int tap = r2 >> 3, c = r2 & 7;
        int ci = g * 8 + c;
        if (o < J.O && ci < J.I) wv = J.src[(o * J.I + ci) * 9 + tap];
    }
    ushort_t h, l;
    split16(wv, h, l);
    J.dst[idx] = h;
    J.dst[total + idx] = l;
}

// ---------------------------------------------------------------------------
// pack fp32 -> packed u32
// ---------------------------------------------------------------------------
__global__ __launch_bounds__(256) void pack_k(const float* __restrict__ src,
                                              unsigned* __restrict__ dst,
                                              int n) {
    int i = blockIdx.x * 256 + threadIdx.x;
    if (i < n) dst[i] = pk(src[i]);
}

// ---------------------------------------------------------------------------
// MFMA implicit-GEMM 3x3 conv, 16x16x32 bf16, 3-term hi/lo split.
// Block: 256 thr = 4 waves; wave tile = 16 out x 16 px.
// ---------------------------------------------------------------------------
__global__ __launch_bounds__(256) void convm_k(
    const void* __restrict__ s0, const void* __restrict__ s1,
    const void* __restrict__ s2, int b0, int b1, int b2, int f32mask,
    int nsrc, const ushort_t* __restrict__ wfrag, int KCfull, int OTtot,
    const float* __restrict__ bias, int Creal,
    const float* __restrict__ addsrc, unsigned* __restrict__ outpk, int act) {
    const int tid = threadIdx.x;
    const int lane = tid & 63;
    const int w = tid >> 6;
    const int xb = (blockIdx.x % 6) * 16;
    const int y = blockIdx.x / 6;
    const int ot = blockIdx.y * 4 + w;
    const int n = lane & 15;
    const int quad = lane >> 4;

    __shared__ __align__(16) ushort_t ldsH[3 * 18 * 72];
    __shared__ __align__(16) ushort_t ldsL[3 * 18 * 72];

    f32x4 acc0, acc1;
#pragma unroll
    for (int r = 0; r < 4; ++r) { acc0[r] = 0.f; acc1[r] = 0.f; }

    const size_t hlOff = (size_t)9 * KCfull * OTtot * 512;

    for (int j = 0; j < nsrc; ++j) {
        const void* sv = (j == 0) ? s0 : (j == 1 ? s1 : s2);
        const int base = (j == 0) ? b0 : (j == 1 ? b1 : b2);
        const bool isf = (f32mask >> j) & 1;
        __syncthreads();
#pragma unroll
        for (int i = 0; i < 14; ++i) {
            int e = tid + i * 256;
            if (e < 3456) {
                int ci = e / 54;
                int rem = e - ci * 54;
                int r = rem / 18;
                int col = rem - r * 18;
                int gy = y - 1 + r, gx = xb - 1 + col;
                unsigned p = 0;
                if ((unsigned)gy < 96u && (unsigned)gx < 96u) {
                    int off = ci * HW96 + gy * 96 + gx;
                    p = isf ? pk(((const float*)sv)[off])
                            : ((const unsigned*)sv)[off];
                }
                int la = (r * 18 + col) * 72 + ci;
                ldsH[la] = (ushort_t)(p >> 16);
                ldsL[la] = (ushort_t)(p & 0xFFFFu);
            }
        }
        __syncthreads();
#pragma unroll
        for (int t = 0; t < 9; ++t) {
            const int ky = t / 3, kx = t % 3;
#pragma unroll
            for (int cc2 = 0; cc2 < 2; ++cc2) {
                const int ccor = base + cc2;
                const ushort_t* ab =
                    wfrag +
                    (((size_t)(t * KCfull + ccor) * OTtot + ot) * 64 + lane) * 8;
                bf16x8 Ah = *(const bf16x8*)ab;
                bf16x8 Al = *(const bf16x8*)(ab + hlOff);
                int lb = (ky * 18 + n + kx) * 72 + cc2 * 32 + quad * 8;
                bf16x8 Bh = *(const bf16x8*)(ldsH + lb);
                bf16x8 Bl = *(const bf16x8*)(ldsL + lb);
                if (t & 1) {
                    acc1 = __builtin_amdgcn_mfma_f32_16x16x32_bf16(Ah, Bh, acc1, 0, 0, 0);
                    acc1 = __builtin_amdgcn_mfma_f32_16x16x32_bf16(Al, Bh, acc1, 0, 0, 0);
                    acc1 = __builtin_amdgcn_mfma_f32_16x16x32_bf16(Ah, Bl, acc1, 0, 0, 0);
                } else {
                    acc0 = __builtin_amdgcn_mfma_f32_16x16x32_bf16(Ah, Bh, acc0, 0, 0, 0);
                    acc0 = __builtin_amdgcn_mfma_f32_16x16x32_bf16(Al, Bh, acc0, 0, 0, 0);
                    acc0 = __builtin_amdgcn_mfma_f32_16x16x32_bf16(Ah, Bl, acc0, 0, 0, 0);
                }
            }
        }
    }

    const int px = y * 96 + xb + n;
#pragma unroll
    for (int r = 0; r < 4; ++r) {
        int cout = ot * 16 + quad * 4 + r;
        if (cout < Creal) {
            float v = acc0[r] + acc1[r] + bias[cout];
            if (act) v = (v >= 0.f) ? v : 0.1f * v;
            if (addsrc) v += addsrc[(size_t)cout * HW96 + px];
            outpk[(size_t)cout * HW96 + px] = pk(v);
        }
    }
}

// ---------------------------------------------------------------------------
// Modulated deformable conv v2, gather->LDS->MFMA.
// Block = 256 thr (4 waves) owns a 16-px row segment and ALL 64 out-ch.
// Gather: each (px, g, tap) job computed once; cols K-index = g*72+tap*8+c,
// stored in LDS as bf16 hi/lo (row stride 296 for bank spread).
// MFMA: wave w -> out tile w; 9 K-chunks per 4-group slab, 3 split terms.
// No atomics: direct fp32 + packed stores.
// ---------------------------------------------------------------------------
__global__ __launch_bounds__(256) void dconv_mfma_k(
    const unsigned* __restrict__ sA, const unsigned* __restrict__ sB,
    const unsigned* __restrict__ raw, const ushort_t* __restrict__ wfrag,
    const float* __restrict__ dbias, int ngr4, float* __restrict__ outf,
    unsigned* __restrict__ outpk) {
    const int tid = threadIdx.x;
    const int lane = tid & 63;
    const int w = tid >> 6;
    const int xb = (blockIdx.x % 6) * 16;
    const int y = blockIdx.x / 6;
    const int n = lane & 15;
    const int quad = lane >> 4;

    __shared__ __align__(16) ushort_t colsH[16 * 296];
    __shared__ __align__(16) ushort_t colsL[16 * 296];

    f32x4 acc0, acc1;
#pragma unroll
    for (int r = 0; r < 4; ++r) { acc0[r] = 0.f; acc1[r] = 0.f; }

    const size_t hlOff = (size_t)36 * 4 * 512;

    for (int gc = 0; gc < ngr4; ++gc) {
        __syncthreads();
        // ---- gather 4 groups (K-slab of 288) ----
#pragma unroll
        for (int i = 0; i < 3; ++i) {
            int e = tid + i * 256;
            if (e < 576) {
                int p = e & 15;
                int r = e >> 4;  // 0..35
                int gl = r / 9, k = r - gl * 9;
                int g = gc * 4 + gl;
                int pidx = y * 96 + xb + p;
                float ry = unpk(raw[(size_t)(g * 18 + k * 2 + 0) * HW96 + pidx]);
                float rx = unpk(raw[(size_t)(g * 18 + k * 2 + 1) * HW96 + pidx]);
                float rm = unpk(raw[(size_t)(288 + g * 9 + k) * HW96 + pidx]);
                float oy = 5.f * (1.f - 2.f / (1.f + __expf(2.f * ry)));
                float ox = 5.f * (1.f - 2.f / (1.f + __expf(2.f * rx)));
                float m = 1.f / (1.f + __expf(-rm));
                float sy = oy + (float)(y - 1 + k / 3);
                float sx = ox + (float)(xb + p - 1 + k % 3);
                float fy0 = floorf(sy), fx0 = floorf(sx);
                float fy = sy - fy0, fx = sx - fx0;
                int y0 = (int)fy0, x0 = (int)fx0;
                int y1 = y0 + 1, x1 = x0 + 1;
                bool vy0 = (unsigned)y0 < 96u, vy1 = (unsigned)y1 < 96u;
                bool vx0 = (unsigned)x0 < 96u, vx1 = (unsigned)x1 < 96u;
                int cy0 = min(max(y0, 0), 95), cy1 = min(max(y1, 0), 95);
                int cx0 = min(max(x0, 0), 95), cx1 = min(max(x1, 0), 95);
                float w00 = (1.f - fy) * (1.f - fx) * ((vy0 && vx0) ? 1.f : 0.f);
                float w01 = (1.f - fy) * fx * ((vy0 && vx1) ? 1.f : 0.f);
                float w10 = fy * (1.f - fx) * ((vy1 && vx0) ? 1.f : 0.f);
                float w11 = fy * fx * ((vy1 && vx1) ? 1.f : 0.f);
                int i00 = cy0 * 96 + cx0, i01 = cy0 * 96 + cx1;
                int i10 = cy1 * 96 + cx0, i11 = cy1 * 96 + cx1;
                const unsigned* src = (g < 8) ? sA : sB;
                int cb = (g & 7) * 8;
                int kbase = p * 296 + gl * 72 + k * 8;
                if (src) {
#pragma unroll
                    for (int c = 0; c < 8; ++c) {
                        const unsigned* plane = src + (size_t)(cb + c) * HW96;
                        float v = w00 * unpk(plane[i00]) +
                                  w01 * unpk(plane[i01]) +
                                  w10 * unpk(plane[i10]) +
                                  w11 * unpk(plane[i11]);
                        float col = v * m;
                        ushort_t h, l;
                        split16(col, h, l);
                        colsH[kbase + c] = h;
                        colsL[kbase + c] = l;
                    }
                } else {
#pragma unroll
                    for (int c = 0; c < 8; ++c) {
                        colsH[kbase + c] = 0;
                        colsL[kbase + c] = 0;
                    }
                }
            }
        }
        __syncthreads();
        // ---- MFMA over this slab: 9 chunks of K=32 ----
#pragma unroll
        for (int cc2 = 0; cc2 < 9; ++cc2) {
            int cc = gc * 9 + cc2;
            const ushort_t* ab = wfrag + (((size_t)cc * 4 + w) * 64 + lane) * 8;
            bf16x8 Ah = *(const bf16x8*)ab;
            bf16x8 Al = *(const bf16x8*)(ab + hlOff);
            int lb = n * 296 + cc2 * 32 + quad * 8;
            bf16x8 Bh = *(const bf16x8*)(colsH + lb);
            bf16x8 Bl = *(const bf16x8*)(colsL + lb);
            if (cc2 & 1) {
                acc1 = __builtin_amdgcn_mfma_f32_16x16x32_bf16(Ah, Bh, acc1, 0, 0, 0);
                acc1 = __builtin_amdgcn_mfma_f32_16x16x32_bf16(Al, Bh, acc1, 0, 0, 0);
                acc1 = __builtin_amdgcn_mfma_f32_16x16x32_bf16(Ah, Bl, acc1, 0, 0, 0);
            } else {
                acc0 = __builtin_amdgcn_mfma_f32_16x16x32_bf16(Ah, Bh, acc0, 0, 0, 0);
                acc0 = __builtin_amdgcn_mfma_f32_16x16x32_bf16(Al, Bh, acc0, 0, 0, 0);
                acc0 = __builtin_amdgcn_mfma_f32_16x16x32_bf16(Ah, Bl, acc0, 0, 0, 0);
            }
        }
    }

    const int pidx = y * 96 + xb + n;
#pragma unroll
    for (int r = 0; r < 4; ++r) {
        int cout = w * 16 + quad * 4 + r;
        float v = acc0[r] + acc1[r] + dbias[cout];
        outf[(size_t)cout * HW96 + pidx] = v;
        outpk[(size_t)cout * HW96 + pidx] = pk(v);
    }
}

// ---------------------------------------------------------------------------
// Fusion: 1x1 conv over [featB[t], featF[t]] (packed) + bias + x, fp32 out.
// ---------------------------------------------------------------------------
__global__ __launch_bounds__(256) void fuse_k(
    const unsigned* __restrict__ featB, const unsigned* __restrict__ featF,
    const float* __restrict__ x, const float* __restrict__ wp,
    const float* __restrict__ bias, float* __restrict__ out) {
    const int tx = threadIdx.x & 31;
    const int ty = threadIdx.x >> 5;
    const int px = blockIdx.x * 32 + tx;
    const int py = blockIdx.y * 8 + ty;
    const int t = blockIdx.z >> 3;
    const int obase = (blockIdx.z & 7) * 8;
    const int pidx = py * 96 + px;
    const unsigned* fB = featB + (size_t)t * FRAME;
    const unsigned* fF = featF + (size_t)t * FRAME;

    float acc[8];
#pragma unroll
    for (int o = 0; o < 8; ++o) acc[o] = 0.f;

    for (int i = 0; i < 64; ++i) {
        float v = unpk(fB[(size_t)i * HW96 + pidx]);
        const float* wr = wp + i * 64 + obase;
#pragma unroll
        for (int o = 0; o < 8; ++o) acc[o] = fmaf(wr[o], v, acc[o]);
    }
    for (int i = 0; i < 64; ++i) {
        float v = unpk(fF[(size_t)i * HW96 + pidx]);
        const float* wr = wp + (64 + i) * 64 + obase;
#pragma unroll
        for (int o = 0; o < 8; ++o) acc[o] = fmaf(wr[o], v, acc[o]);
    }
    const float* xt = x + (size_t)t * FRAME;
#pragma unroll
    for (int o = 0; o < 8; ++o)
        out[(size_t)t * FRAME + (size_t)(obase + o) * HW96 + pidx] =
            acc[o] + bias[obase + o] + xt[(size_t)(obase + o) * HW96 + pidx];
}

// ---------------------------------------------------------------------------
extern "C" void kernel_launch(void* const* d_in, const int* in_sizes, int n_in,
                              void* d_out, int out_size, void* d_ws,
                              size_t ws_size, hipStream_t stream) {
    const float* x = (const float*)d_in[0];
    auto gp = [&](int i) { return (const float*)d_in[i]; };

    struct DirP {
        const float *dw, *db, *ow1, *ob1, *ow2, *ob2, *ow3, *ob3, *ow4, *ob4,
            *bw1, *bb1, *bw2, *bb2;
    };
    DirP Pb{gp(1), gp(2), gp(3), gp(4), gp(5), gp(6), gp(7),
            gp(8), gp(9), gp(10), gp(11), gp(12), gp(13), gp(14)};
    DirP Pf{gp(15), gp(16), gp(17), gp(18), gp(19), gp(20), gp(21),
            gp(22), gp(23), gp(24), gp(25), gp(26), gp(27), gp(28)};
    const float* fus_w = gp(29);
    const float* fus_b = gp(30);

    // ---- workspace carve-up (4-byte units) ----
    unsigned* featBpk = (unsigned*)d_ws;
    unsigned* featFpk = featBpk + (size_t)8 * FRAME;
    unsigned* xpk = featFpk + (size_t)8 * FRAME;
    float* Dbuf = (float*)(xpk + (size_t)8 * FRAME);
    unsigned* Dpk = (unsigned*)(Dbuf + FRAME);
    unsigned* hApk = Dpk + FRAME;
    unsigned* hBpk = hApk + FRAME;
    unsigned* b432pk = hBpk + FRAME;  // 432 planes
    float* wfus = (float*)(b432pk + (size_t)432 * HW96);
    ushort_t* fragp = (ushort_t*)(wfus + 128 * 64);

    auto falloc = [&](size_t nelem) {
        ushort_t* p = fragp;
        fragp += nelem;
        return p;
    };

    // ---- weight prep ----
    repack_fus_k<<<32, 256, 0, stream>>>(fus_w, wfus);

    struct DirW { ushort_t *ow1, *ow2, *ow3, *ow4, *bw1, *bw2, *dw; int bw1KC; };
    FragJobs fj;
    int nf = 0;
    auto fjob = [&](const float* src, int O, int I, int OT, int KC) {
        ushort_t* dst = falloc((size_t)2 * 9 * KC * OT * 512);
        fj.j[nf++] = FragJob{src, dst, O, I, OT, KC, 0};
        return dst;
    };
    auto fjobd = [&](const float* src) {
        ushort_t* dst = falloc((size_t)2 * 36 * 4 * 512);
        fj.j[nf++] = FragJob{src, dst, 64, 128, 4, 36, 1};
        return dst;
    };
    DirW Wb, Wf;
    Wb.ow1 = fjob(Pb.ow1, 64, 192, 4, 6);
    Wb.ow2 = fjob(Pb.ow2, 64, 64, 4, 2);
    Wb.ow3 = fjob(Pb.ow3, 64, 64, 4, 2);
    Wb.ow4 = fjob(Pb.ow4, 432, 64, 28, 2);
    Wb.bw1 = fjob(Pb.bw1, 64, 128, 4, 4);
    Wb.bw1KC = 4;
    Wb.bw2 = fjob(Pb.bw2, 64, 64, 4, 2);
    Wb.dw = fjobd(Pb.dw);
    Wf.ow1 = fjob(Pf.ow1, 64, 192, 4, 6);
    Wf.ow2 = fjob(Pf.ow2, 64, 64, 4, 2);
    Wf.ow3 = fjob(Pf.ow3, 64, 64, 4, 2);
    Wf.ow4 = fjob(Pf.ow4, 432, 64, 28, 2);
    Wf.bw1 = fjob(Pf.bw1, 64, 192, 4, 6);
    Wf.bw1KC = 6;
    Wf.bw2 = fjob(Pf.bw2, 64, 64, 4, 2);
    Wf.dw = fjobd(Pf.dw);
    frag_all_k<<<dim3(1008, 14), 256, 0, stream>>>(fj);

    pack_k<<<(8 * FRAME + 255) / 256, 256, 0, stream>>>(x, xpk, 8 * FRAME);

    struct Src { const void* p; int f; };
    auto convm = [&](Src a, Src b, Src c2, const ushort_t* frag, int KCfull,
                     int OT, const float* bias, int Creal,
                     const float* addsrc, unsigned* out, int act) {
        Src srcs[3] = {a, b, c2};
        const void* S[3] = {nullptr, nullptr, nullptr};
        int B[3] = {0, 0, 0};
        int mask = 0, ns = 0;
        for (int j = 0; j < 3; ++j)
            if (srcs[j].p) {
                S[ns] = srcs[j].p;
                B[ns] = j * 2;
                if (srcs[j].f) mask |= (1 << ns);
                ++ns;
            }
        dim3 g(576, OT / 4);
        convm_k<<<g, 256, 0, stream>>>(S[0], S[1], S[2], B[0], B[1], B[2],
                                       mask, ns, frag, KCfull, OT, bias,
                                       Creal, addsrc, out, act);
    };
    Src NONE{nullptr, 0};

    for (int dir = 0; dir < 2; ++dir) {  // 0 = backward, 1 = forward
        const DirP& P = dir ? Pf : Pb;
        const DirW& W = dir ? Wf : Wb;
        unsigned* feat = dir ? featFpk : featBpk;
        const unsigned* prev1 = nullptr;
        const unsigned* prev2 = nullptr;
        for (int i = 0; i < 8; ++i) {
            int idx = dir ? i : 7 - i;
            const unsigned* cur = xpk + (size_t)idx * FRAME;
            const float* propf = nullptr;  // fp32 dconv output
            if (i > 0) {
                convm(Src{prev1, 0}, Src{cur, 0}, Src{prev2, 0}, W.ow1, 6, 4,
                      P.ob1, 64, nullptr, hApk, 1);
                convm(Src{hApk, 0}, NONE, NONE, W.ow2, 2, 4, P.ob2, 64,
                      nullptr, hBpk, 1);
                convm(Src{hBpk, 0}, NONE, NONE, W.ow3, 2, 4, P.ob3, 64,
                      nullptr, hApk, 1);
                convm(Src{hApk, 0}, NONE, NONE, W.ow4, 2, 28, P.ob4, 432,
                      nullptr, b432pk, 0);
                int ngr4 = (prev2 != nullptr) ? 4 : 2;
                dconv_mfma_k<<<576, 256, 0, stream>>>(
                    prev1, prev2, b432pk, W.dw, P.db, ngr4, Dbuf, Dpk);
                propf = Dbuf;
            }
            unsigned* dst = feat + (size_t)idx * FRAME;
            if (dir == 0) {
                convm(Src{cur, 0}, (i > 0) ? Src{Dpk, 0} : NONE, NONE, W.bw1,
                      W.bw1KC, 4, P.bb1, 64, nullptr, hBpk, 1);
            } else {
                convm(Src{cur, 0}, Src{featBpk + (size_t)idx * FRAME, 0},
                      (i > 0) ? Src{Dpk, 0} : NONE, W.bw1, W.bw1KC, 4, P.bb1,
                      64, nullptr, hBpk, 1);
            }
            convm(Src{hBpk, 0}, NONE, NONE, W.bw2, 2, 4, P.bb2, 64, propf,
                  dst, 0);
            prev2 = prev1;
            prev1 = dst;
        }
    }

    fuse_k<<<dim3(3, 12, 64), 256, 0, stream>>>(featBpk, featFpk, x, wfus,
                                                fus_b, (float*)d_out);
}

// Round 7
// 2710.256 us; speedup vs baseline: 4.8903x; 1.0870x over previous
//
#include <hip/hip_runtime.h>
#include <cstddef>

#define HW96 9216
#define FRAME (64 * 9216)

typedef unsigned short ushort_t;
typedef __attribute__((ext_vector_type(8))) short bf16x8;
typedef __attribute__((ext_vector_type(4))) float f32x4;
typedef __attribute__((ext_vector_type(4))) unsigned u32x4;

// packed u32 = (bf16 hi bits << 16) | bf16 lo bits; value = hi + lo exactly
__device__ __forceinline__ float unpk(unsigned p) {
    return __uint_as_float(p & 0xFFFF0000u) + __uint_as_float(p << 16);
}
__device__ __forceinline__ unsigned pk(float v) {
    unsigned u = __float_as_uint(v);
    unsigned hi = u & 0xFFFF0000u;
    float rem = v - __uint_as_float(hi);
    unsigned r = __float_as_uint(rem);
    unsigned lo = (r + 0x7FFFu + ((r >> 16) & 1u)) >> 16;
    return hi | (lo & 0xFFFFu);
}
__device__ __forceinline__ void split16(float v, ushort_t& h, ushort_t& l) {
    unsigned u = __float_as_uint(v);
    h = (ushort_t)(u >> 16);
    float rem = v - __uint_as_float(u & 0xFFFF0000u);
    unsigned r = __float_as_uint(rem);
    l = (ushort_t)((r + 0x7FFFu + ((r >> 16) & 1u)) >> 16);
}

// ---------------------------------------------------------------------------
// Plain repack: OIHW -> [i][o] fp32 (fusion 1x1 only).
// ---------------------------------------------------------------------------
__global__ __launch_bounds__(256) void repack_fus_k(const float* __restrict__ w,
                                                    float* __restrict__ wp) {
    int idx = blockIdx.x * 256 + threadIdx.x;  // 128*64
    if (idx >= 128 * 64) return;
    int o = idx % 64;
    int i = idx / 64;
    wp[idx] = w[o * 128 + i];
}

// ---------------------------------------------------------------------------
// MFMA A-fragment prepack (16x16x32) with bf16 hi/lo split.
// mode 0 (3x3 conv): layout [hl][t][cc][ot][lane][j]; K = cin chunks of 32.
// mode 1 (dconv):    layout [hl][cc][ot][lane][j]; K = g*72 + tap*8 + c.
// A[m=lane&15][k=(lane>>4)*8+j].
// ---------------------------------------------------------------------------
struct FragJob { const float* src; ushort_t* dst; int O, I, OT, KC, mode; };
struct FragJobs { FragJob j[14]; };

__global__ __launch_bounds__(256) void frag_all_k(FragJobs jobs) {
    const FragJob& J = jobs.j[blockIdx.y];
    int idx = blockIdx.x * 256 + threadIdx.x;
    int total = (J.mode ? 1 : 9) * J.KC * J.OT * 512;
    if (idx >= total) return;
    int jj = idx & 7;
    int lane = (idx >> 3) & 63;
    int rem = idx >> 9;
    int ot = rem % J.OT;
    rem /= J.OT;
    int cc = rem % J.KC;
    int t = rem / J.KC;
    int o = ot * 16 + (lane & 15);
    float wv = 0.f;
    if (J.mode == 0) {
        int ci = cc * 32 + (lane >> 4) * 8 + jj;
        if (o < J.O && ci < J.I) wv = J.src[(o * J.I + ci) * 9 + t];
    } else {
        int K = cc * 32 + (lane >> 4) * 8 + jj;
        int g = K / 72, r2 = K % 72;
        int tap = r2 >> 3, c = r2 & 7;
        int ci = g * 8 + c;
        if (o < J.O && ci < J.I) wv = J.src[(o * J.I + ci) * 9 + tap];
    }
    ushort_t h, l;
    split16(wv, h, l);
    J.dst[idx] = h;
    J.dst[total + idx] = l;
}

// ---------------------------------------------------------------------------
// pack fp32 -> packed u32
// ---------------------------------------------------------------------------
__global__ __launch_bounds__(256) void pack_k(const float* __restrict__ src,
                                              unsigned* __restrict__ dst,
                                              int n) {
    int i = blockIdx.x * 256 + threadIdx.x;
    if (i < n) dst[i] = pk(src[i]);
}

// ---------------------------------------------------------------------------
// MFMA implicit-GEMM 3x3 conv, 16x16x32 bf16, 3-term hi/lo split.
// Block: 256 thr = 4 waves; wave tile = 16 out x 16 px.
// Staging: 432 jobs = 54 (row,col) positions x 8 ci-octets; 8 independent 4B
// loads -> two 16B LDS writes (conflict-free).
// ---------------------------------------------------------------------------
__global__ __launch_bounds__(256) void convm_k(
    const void* __restrict__ s0, const void* __restrict__ s1,
    const void* __restrict__ s2, int b0, int b1, int b2, int f32mask,
    int nsrc, const ushort_t* __restrict__ wfrag, int KCfull, int OTtot,
    const float* __restrict__ bias, int Creal,
    const float* __restrict__ addsrc, unsigned* __restrict__ outpk, int act) {
    const int tid = threadIdx.x;
    const int lane = tid & 63;
    const int w = tid >> 6;
    const int xb = (blockIdx.x % 6) * 16;
    const int y = blockIdx.x / 6;
    const int ot = blockIdx.y * 4 + w;
    const int n = lane & 15;
    const int quad = lane >> 4;

    __shared__ __align__(16) ushort_t ldsH[3 * 18 * 72];
    __shared__ __align__(16) ushort_t ldsL[3 * 18 * 72];

    // staging job decode (loop-invariant)
    int jst[2], jok[2], jpo[2], jbase[2], jcg[2];
#pragma unroll
    for (int i = 0; i < 2; ++i) {
        int e = tid + i * 256;
        int rc = e >> 3, cg = e & 7;
        int r = rc / 18, col = rc - r * 18;
        int gy = y - 1 + r, gx = xb - 1 + col;
        jst[i] = (e < 432);
        jok[i] = jst[i] && ((unsigned)gy < 96u) && ((unsigned)gx < 96u);
        jpo[i] = gy * 96 + gx;
        jbase[i] = rc * 72 + cg * 8;
        jcg[i] = cg * 8;
    }

    f32x4 acc0, acc1;
#pragma unroll
    for (int r = 0; r < 4; ++r) { acc0[r] = 0.f; acc1[r] = 0.f; }

    const size_t hlOff = (size_t)9 * KCfull * OTtot * 512;

    for (int j = 0; j < nsrc; ++j) {
        const void* sv = (j == 0) ? s0 : (j == 1 ? s1 : s2);
        const int base = (j == 0) ? b0 : (j == 1 ? b1 : b2);
        const bool isf = (f32mask >> j) & 1;
        __syncthreads();
#pragma unroll
        for (int i = 0; i < 2; ++i) {
            if (jst[i]) {
                unsigned p[8];
#pragma unroll
                for (int c = 0; c < 8; ++c) {
                    unsigned v = 0;
                    if (jok[i]) {
                        int off = (jcg[i] + c) * HW96 + jpo[i];
                        v = isf ? pk(((const float*)sv)[off])
                                : ((const unsigned*)sv)[off];
                    }
                    p[c] = v;
                }
                u32x4 H, L;
#pragma unroll
                for (int q = 0; q < 4; ++q) {
                    H[q] = (p[2 * q] >> 16) | (p[2 * q + 1] & 0xFFFF0000u);
                    L[q] = (p[2 * q] & 0xFFFFu) | (p[2 * q + 1] << 16);
                }
                *(u32x4*)(ldsH + jbase[i]) = H;
                *(u32x4*)(ldsL + jbase[i]) = L;
            }
        }
        __syncthreads();
#pragma unroll
        for (int t = 0; t < 9; ++t) {
            const int ky = t / 3, kx = t % 3;
#pragma unroll
            for (int cc2 = 0; cc2 < 2; ++cc2) {
                const int ccor = base + cc2;
                const ushort_t* ab =
                    wfrag +
                    (((size_t)(t * KCfull + ccor) * OTtot + ot) * 64 + lane) * 8;
                bf16x8 Ah = *(const bf16x8*)ab;
                bf16x8 Al = *(const bf16x8*)(ab + hlOff);
                int lb = (ky * 18 + n + kx) * 72 + cc2 * 32 + quad * 8;
                bf16x8 Bh = *(const bf16x8*)(ldsH + lb);
                bf16x8 Bl = *(const bf16x8*)(ldsL + lb);
                if (t & 1) {
                    acc1 = __builtin_amdgcn_mfma_f32_16x16x32_bf16(Ah, Bh, acc1, 0, 0, 0);
                    acc1 = __builtin_amdgcn_mfma_f32_16x16x32_bf16(Al, Bh, acc1, 0, 0, 0);
                    acc1 = __builtin_amdgcn_mfma_f32_16x16x32_bf16(Ah, Bl, acc1, 0, 0, 0);
                } else {
                    acc0 = __builtin_amdgcn_mfma_f32_16x16x32_bf16(Ah, Bh, acc0, 0, 0, 0);
                    acc0 = __builtin_amdgcn_mfma_f32_16x16x32_bf16(Al, Bh, acc0, 0, 0, 0);
                    acc0 = __builtin_amdgcn_mfma_f32_16x16x32_bf16(Ah, Bl, acc0, 0, 0, 0);
                }
            }
        }
    }

    const int px = y * 96 + xb + n;
#pragma unroll
    for (int r = 0; r < 4; ++r) {
        int cout = ot * 16 + quad * 4 + r;
        if (cout < Creal) {
            float v = acc0[r] + acc1[r] + bias[cout];
            if (act) v = (v >= 0.f) ? v : 0.1f * v;
            if (addsrc) v += addsrc[(size_t)cout * HW96 + px];
            outpk[(size_t)cout * HW96 + px] = pk(v);
        }
    }
}

// ---------------------------------------------------------------------------
// Fused ow4 (64->432 conv) + modulated deformable conv v2.
// Each raw[g,k][px] is consumed exactly once by the gather at the same px,
// so fusing duplicates nothing. Block = 256 thr (4 waves), 16-px row seg.
// Phase 1: stage hA 3x18x64 window (hi/lo) in LDS.
// Phase 2: MFMA raw[448][16] (ow4, bias, no act) -> LDS fp32.
// Phase 3: gather (offsets/mask from LDS raw) -> cols -> dconv MFMA.
// LDS: [staging | cols (union, 18944 B)][rawS 28672 B] = 46.5 KB.
// ---------------------------------------------------------------------------
__global__ __launch_bounds__(256) void dconv_fused_k(
    const unsigned* __restrict__ sA, const unsigned* __restrict__ sB,
    const unsigned* __restrict__ hA, const ushort_t* __restrict__ w4,
    const float* __restrict__ ob4, const ushort_t* __restrict__ dwf,
    const float* __restrict__ dbias, int ngr4, float* __restrict__ outf) {
    const int tid = threadIdx.x;
    const int lane = tid & 63;
    const int w = tid >> 6;
    const int xb = (blockIdx.x % 6) * 16;
    const int y = blockIdx.x / 6;
    const int n = lane & 15;
    const int quad = lane >> 4;

    __shared__ __align__(16) char smem[18944 + 28672];
    ushort_t* ldsAH = (ushort_t*)smem;        // 3888 ushorts
    ushort_t* ldsAL = ldsAH + 3888;           // ends at 15552 B
    ushort_t* colsH = (ushort_t*)smem;        // 16*296 = 4736 ushorts
    ushort_t* colsL = colsH + 4736;           // ends at 18944 B
    float* rawS = (float*)(smem + 18944);     // 448*16 fp32

    // ---- phase 1: stage hA window ----
    {
#pragma unroll
        for (int i = 0; i < 2; ++i) {
            int e = tid + i * 256;
            if (e < 432) {
                int rc = e >> 3, cg = e & 7;
                int r = rc / 18, col = rc - r * 18;
                int gy = y - 1 + r, gx = xb - 1 + col;
                bool ok = ((unsigned)gy < 96u) && ((unsigned)gx < 96u);
                int po = gy * 96 + gx;
                unsigned p[8];
#pragma unroll
                for (int c = 0; c < 8; ++c)
                    p[c] = ok ? hA[(cg * 8 + c) * HW96 + po] : 0u;
                u32x4 H, L;
#pragma unroll
                for (int q = 0; q < 4; ++q) {
                    H[q] = (p[2 * q] >> 16) | (p[2 * q + 1] & 0xFFFF0000u);
                    L[q] = (p[2 * q] & 0xFFFFu) | (p[2 * q + 1] << 16);
                }
                *(u32x4*)(ldsAH + rc * 72 + cg * 8) = H;
                *(u32x4*)(ldsAL + rc * 72 + cg * 8) = L;
            }
        }
    }
    __syncthreads();

    // ---- phase 2: raw = ow4(hA), 7 out-tiles per wave ----
    const size_t hl4 = (size_t)9 * 2 * 28 * 512;
#pragma unroll 1
    for (int j = 0; j < 7; ++j) {
        const int ot = j * 4 + w;
        f32x4 a0, a1;
#pragma unroll
        for (int r = 0; r < 4; ++r) { a0[r] = 0.f; a1[r] = 0.f; }
#pragma unroll
        for (int t = 0; t < 9; ++t) {
            const int ky = t / 3, kx = t % 3;
#pragma unroll
            for (int cc2 = 0; cc2 < 2; ++cc2) {
                const ushort_t* ab =
                    w4 + (((size_t)(t * 2 + cc2) * 28 + ot) * 64 + lane) * 8;
                bf16x8 Ah = *(const bf16x8*)ab;
                bf16x8 Al = *(const bf16x8*)(ab + hl4);
                int lb = (ky * 18 + n + kx) * 72 + cc2 * 32 + quad * 8;
                bf16x8 Bh = *(const bf16x8*)(ldsAH + lb);
                bf16x8 Bl = *(const bf16x8*)(ldsAL + lb);
                if ((t * 2 + cc2) & 1) {
                    a1 = __builtin_amdgcn_mfma_f32_16x16x32_bf16(Ah, Bh, a1, 0, 0, 0);
                    a1 = __builtin_amdgcn_mfma_f32_16x16x32_bf16(Al, Bh, a1, 0, 0, 0);
                    a1 = __builtin_amdgcn_mfma_f32_16x16x32_bf16(Ah, Bl, a1, 0, 0, 0);
                } else {
                    a0 = __builtin_amdgcn_mfma_f32_16x16x32_bf16(Ah, Bh, a0, 0, 0, 0);
                    a0 = __builtin_amdgcn_mfma_f32_16x16x32_bf16(Al, Bh, a0, 0, 0, 0);
                    a0 = __builtin_amdgcn_mfma_f32_16x16x32_bf16(Ah, Bl, a0, 0, 0, 0);
                }
            }
        }
#pragma unroll
        for (int r = 0; r < 4; ++r) {
            int cout = ot * 16 + quad * 4 + r;
            float v = a0[r] + a1[r] + (cout < 432 ? ob4[cout] : 0.f);
            rawS[cout * 16 + n] = v;
        }
    }

    // ---- phase 3: gather + dconv MFMA ----
    f32x4 acc0, acc1;
#pragma unroll
    for (int r = 0; r < 4; ++r) { acc0[r] = 0.f; acc1[r] = 0.f; }
    const size_t hlD = (size_t)36 * 4 * 512;

    for (int gc = 0; gc < ngr4; ++gc) {
        __syncthreads();  // rawS ready / cols+ldsA reuse safe
#pragma unroll
        for (int i = 0; i < 3; ++i) {
            int e = tid + i * 256;
            if (e < 576) {
                int p = e & 15;
                int r = e >> 4;  // 0..35
                int gl = r / 9, k = r - gl * 9;
                int g = gc * 4 + gl;
                float ry = rawS[(g * 18 + k * 2 + 0) * 16 + p];
                float rx = rawS[(g * 18 + k * 2 + 1) * 16 + p];
                float rm = rawS[(288 + g * 9 + k) * 16 + p];
                float oy = 5.f * (1.f - 2.f / (1.f + __expf(2.f * ry)));
                float ox = 5.f * (1.f - 2.f / (1.f + __expf(2.f * rx)));
                float m = 1.f / (1.f + __expf(-rm));
                float sy = oy + (float)(y - 1 + k / 3);
                float sx = ox + (float)(xb + p - 1 + k % 3);
                float fy0 = floorf(sy), fx0 = floorf(sx);
                float fy = sy - fy0, fx = sx - fx0;
                int y0 = (int)fy0, x0 = (int)fx0;
                int y1 = y0 + 1, x1 = x0 + 1;
                bool vy0 = (unsigned)y0 < 96u, vy1 = (unsigned)y1 < 96u;
                bool vx0 = (unsigned)x0 < 96u, vx1 = (unsigned)x1 < 96u;
                int cy0 = min(max(y0, 0), 95), cy1 = min(max(y1, 0), 95);
                int cx0 = min(max(x0, 0), 95), cx1 = min(max(x1, 0), 95);
                float w00 = (1.f - fy) * (1.f - fx) * ((vy0 && vx0) ? 1.f : 0.f);
                float w01 = (1.f - fy) * fx * ((vy0 && vx1) ? 1.f : 0.f);
                float w10 = fy * (1.f - fx) * ((vy1 && vx0) ? 1.f : 0.f);
                float w11 = fy * fx * ((vy1 && vx1) ? 1.f : 0.f);
                int i00 = cy0 * 96 + cx0, i01 = cy0 * 96 + cx1;
                int i10 = cy1 * 96 + cx0, i11 = cy1 * 96 + cx1;
                const unsigned* src = (g < 8) ? sA : sB;
                int cb = (g & 7) * 8;
                int kbase = p * 296 + gl * 72 + k * 8;
                ushort_t hh[8], ll[8];
                if (src) {
#pragma unroll
                    for (int c = 0; c < 8; ++c) {
                        const unsigned* plane = src + (size_t)(cb + c) * HW96;
                        float v = w00 * unpk(plane[i00]) +
                                  w01 * unpk(plane[i01]) +
                                  w10 * unpk(plane[i10]) +
                                  w11 * unpk(plane[i11]);
                        split16(v * m, hh[c], ll[c]);
                    }
                } else {
#pragma unroll
                    for (int c = 0; c < 8; ++c) { hh[c] = 0; ll[c] = 0; }
                }
                u32x4 H, L;
#pragma unroll
                for (int q = 0; q < 4; ++q) {
                    H[q] = (unsigned)hh[2 * q] | ((unsigned)hh[2 * q + 1] << 16);
                    L[q] = (unsigned)ll[2 * q] | ((unsigned)ll[2 * q + 1] << 16);
                }
                *(u32x4*)(colsH + kbase) = H;
                *(u32x4*)(colsL + kbase) = L;
            }
        }
        __syncthreads();
#pragma unroll
        for (int cc2 = 0; cc2 < 9; ++cc2) {
            int cc = gc * 9 + cc2;
            const ushort_t* ab = dwf + (((size_t)cc * 4 + w) * 64 + lane) * 8;
            bf16x8 Ah = *(const bf16x8*)ab;
            bf16x8 Al = *(const bf16x8*)(ab + hlD);
            int lb = n * 296 + cc2 * 32 + quad * 8;
            bf16x8 Bh = *(const bf16x8*)(colsH + lb);
            bf16x8 Bl = *(const bf16x8*)(colsL + lb);
            if (cc2 & 1) {
                acc1 = __builtin_amdgcn_mfma_f32_16x16x32_bf16(Ah, Bh, acc1, 0, 0, 0);
                acc1 = __builtin_amdgcn_mfma_f32_16x16x32_bf16(Al, Bh, acc1, 0, 0, 0);
                acc1 = __builtin_amdgcn_mfma_f32_16x16x32_bf16(Ah, Bl, acc1, 0, 0, 0);
            } else {
                acc0 = __builtin_amdgcn_mfma_f32_16x16x32_bf16(Ah, Bh, acc0, 0, 0, 0);
                acc0 = __builtin_amdgcn_mfma_f32_16x16x32_bf16(Al, Bh, acc0, 0, 0, 0);
                acc0 = __builtin_amdgcn_mfma_f32_16x16x32_bf16(Ah, Bl, acc0, 0, 0, 0);
            }
        }
    }

    const int pidx = y * 96 + xb + n;
#pragma unroll
    for (int r = 0; r < 4; ++r) {
        int cout = w * 16 + quad * 4 + r;
        outf[(size_t)cout * HW96 + pidx] = acc0[r] + acc1[r] + dbias[cout];
    }
}

// ---------------------------------------------------------------------------
// Fusion: 1x1 conv over [featB[t], featF[t]] (packed) + bias + x, fp32 out.
// ---------------------------------------------------------------------------
__global__ __launch_bounds__(256) void fuse_k(
    const unsigned* __restrict__ featB, const unsigned* __restrict__ featF,
    const float* __restrict__ x, const float* __restrict__ wp,
    const float* __restrict__ bias, float* __restrict__ out) {
    const int tx = threadIdx.x & 31;
    const int ty = threadIdx.x >> 5;
    const int px = blockIdx.x * 32 + tx;
    const int py = blockIdx.y * 8 + ty;
    const int t = blockIdx.z >> 3;
    const int obase = (blockIdx.z & 7) * 8;
    const int pidx = py * 96 + px;
    const unsigned* fB = featB + (size_t)t * FRAME;
    const unsigned* fF = featF + (size_t)t * FRAME;

    float acc[8];
#pragma unroll
    for (int o = 0; o < 8; ++o) acc[o] = 0.f;

    for (int i = 0; i < 64; ++i) {
        float v = unpk(fB[(size_t)i * HW96 + pidx]);
        const float* wr = wp + i * 64 + obase;
#pragma unroll
        for (int o = 0; o < 8; ++o) acc[o] = fmaf(wr[o], v, acc[o]);
    }
    for (int i = 0; i < 64; ++i) {
        float v = unpk(fF[(size_t)i * HW96 + pidx]);
        const float* wr = wp + (64 + i) * 64 + obase;
#pragma unroll
        for (int o = 0; o < 8; ++o) acc[o] = fmaf(wr[o], v, acc[o]);
    }
    const float* xt = x + (size_t)t * FRAME;
#pragma unroll
    for (int o = 0; o < 8; ++o)
        out[(size_t)t * FRAME + (size_t)(obase + o) * HW96 + pidx] =
            acc[o] + bias[obase + o] + xt[(size_t)(obase + o) * HW96 + pidx];
}

// ---------------------------------------------------------------------------
extern "C" void kernel_launch(void* const* d_in, const int* in_sizes, int n_in,
                              void* d_out, int out_size, void* d_ws,
                              size_t ws_size, hipStream_t stream) {
    const float* x = (const float*)d_in[0];
    auto gp = [&](int i) { return (const float*)d_in[i]; };

    struct DirP {
        const float *dw, *db, *ow1, *ob1, *ow2, *ob2, *ow3, *ob3, *ow4, *ob4,
            *bw1, *bb1, *bw2, *bb2;
    };
    DirP Pb{gp(1), gp(2), gp(3), gp(4), gp(5), gp(6), gp(7),
            gp(8), gp(9), gp(10), gp(11), gp(12), gp(13), gp(14)};
    DirP Pf{gp(15), gp(16), gp(17), gp(18), gp(19), gp(20), gp(21),
            gp(22), gp(23), gp(24), gp(25), gp(26), gp(27), gp(28)};
    const float* fus_w = gp(29);
    const float* fus_b = gp(30);

    // ---- workspace carve-up (4-byte units) ----
    unsigned* featBpk = (unsigned*)d_ws;
    unsigned* featFpk = featBpk + (size_t)8 * FRAME;
    unsigned* xpk = featFpk + (size_t)8 * FRAME;
    float* Dbuf = (float*)(xpk + (size_t)8 * FRAME);
    unsigned* hApk = (unsigned*)(Dbuf + FRAME);
    unsigned* hBpk = hApk + FRAME;
    float* wfus = (float*)(hBpk + FRAME);
    ushort_t* fragp = (ushort_t*)(wfus + 128 * 64);

    auto falloc = [&](size_t nelem) {
        ushort_t* p = fragp;
        fragp += nelem;
        return p;
    };

    // ---- weight prep ----
    repack_fus_k<<<32, 256, 0, stream>>>(fus_w, wfus);

    struct DirW { ushort_t *ow1, *ow2, *ow3, *ow4, *bw1, *bw2, *dw; int bw1KC; };
    FragJobs fj;
    int nf = 0;
    auto fjob = [&](const float* src, int O, int I, int OT, int KC) {
        ushort_t* dst = falloc((size_t)2 * 9 * KC * OT * 512);
        fj.j[nf++] = FragJob{src, dst, O, I, OT, KC, 0};
        return dst;
    };
    auto fjobd = [&](const float* src) {
        ushort_t* dst = falloc((size_t)2 * 36 * 4 * 512);
        fj.j[nf++] = FragJob{src, dst, 64, 128, 4, 36, 1};
        return dst;
    };
    DirW Wb, Wf;
    Wb.ow1 = fjob(Pb.ow1, 64, 192, 4, 6);
    Wb.ow2 = fjob(Pb.ow2, 64, 64, 4, 2);
    Wb.ow3 = fjob(Pb.ow3, 64, 64, 4, 2);
    Wb.ow4 = fjob(Pb.ow4, 432, 64, 28, 2);
    Wb.bw1 = fjob(Pb.bw1, 64, 128, 4, 4);
    Wb.bw1KC = 4;
    Wb.bw2 = fjob(Pb.bw2, 64, 64, 4, 2);
    Wb.dw = fjobd(Pb.dw);
    Wf.ow1 = fjob(Pf.ow1, 64, 192, 4, 6);
    Wf.ow2 = fjob(Pf.ow2, 64, 64, 4, 2);
    Wf.ow3 = fjob(Pf.ow3, 64, 64, 4, 2);
    Wf.ow4 = fjob(Pf.ow4, 432, 64, 28, 2);
    Wf.bw1 = fjob(Pf.bw1, 64, 192, 4, 6);
    Wf.bw1KC = 6;
    Wf.bw2 = fjob(Pf.bw2, 64, 64, 4, 2);
    Wf.dw = fjobd(Pf.dw);
    frag_all_k<<<dim3(1008, 14), 256, 0, stream>>>(fj);

    pack_k<<<(8 * FRAME + 255) / 256, 256, 0, stream>>>(x, xpk, 8 * FRAME);

    struct Src { const void* p; int f; };
    auto convm = [&](Src a, Src b, Src c2, const ushort_t* frag, int KCfull,
                     int OT, const float* bias, int Creal,
                     const float* addsrc, unsigned* out, int act) {
        Src srcs[3] = {a, b, c2};
        const void* S[3] = {nullptr, nullptr, nullptr};
        int B[3] = {0, 0, 0};
        int mask = 0, ns = 0;
        for (int j = 0; j < 3; ++j)
            if (srcs[j].p) {
                S[ns] = srcs[j].p;
                B[ns] = j * 2;
                if (srcs[j].f) mask |= (1 << ns);
                ++ns;
            }
        dim3 g(576, OT / 4);
        convm_k<<<g, 256, 0, stream>>>(S[0], S[1], S[2], B[0], B[1], B[2],
                                       mask, ns, frag, KCfull, OT, bias,
                                       Creal, addsrc, out, act);
    };
    Src NONE{nullptr, 0};

    for (int dir = 0; dir < 2; ++dir) {  // 0 = backward, 1 = forward
        const DirP& P = dir ? Pf : Pb;
        const DirW& W = dir ? Wf : Wb;
        unsigned* feat = dir ? featFpk : featBpk;
        const unsigned* prev1 = nullptr;
        const unsigned* prev2 = nullptr;
        for (int i = 0; i < 8; ++i) {
            int idx = dir ? i : 7 - i;
            const unsigned* cur = xpk + (size_t)idx * FRAME;
            const float* propf = nullptr;  // fp32 dconv output
            if (i > 0) {
                convm(Src{prev1, 0}, Src{cur, 0}, Src{prev2, 0}, W.ow1, 6, 4,
                      P.ob1, 64, nullptr, hApk, 1);
                convm(Src{hApk, 0}, NONE, NONE, W.ow2, 2, 4, P.ob2, 64,
                      nullptr, hBpk, 1);
                convm(Src{hBpk, 0}, NONE, NONE, W.ow3, 2, 4, P.ob3, 64,
                      nullptr, hApk, 1);
                int ngr4 = (prev2 != nullptr) ? 4 : 2;
                dconv_fused_k<<<576, 256, 0, stream>>>(
                    prev1, prev2, hApk, W.ow4, P.ob4, W.dw, P.db, ngr4, Dbuf);
                propf = Dbuf;
            }
            unsigned* dst = feat + (size_t)idx * FRAME;
            if (dir == 0) {
                convm(Src{cur, 0}, (i > 0) ? Src{Dbuf, 1} : NONE, NONE, W.bw1,
                      W.bw1KC, 4, P.bb1, 64, nullptr, hBpk, 1);
            } else {
                convm(Src{cur, 0}, Src{featBpk + (size_t)idx * FRAME, 0},
                      (i > 0) ? Src{Dbuf, 1} : NONE, W.bw1, W.bw1KC, 4, P.bb1,
                      64, nullptr, hBpk, 1);
            }
            convm(Src{hBpk, 0}, NONE, NONE, W.bw2, 2, 4, P.bb2, 64, propf,
                  dst, 0);
            prev2 = prev1;
            prev1 = dst;
        }
    }

    fuse_k<<<dim3(3, 12, 64), 256, 0, stream>>>(featBpk, featFpk, x, wfus,
                                                fus_b, (float*)d_out);
}

// Round 8
// 1847.771 us; speedup vs baseline: 7.1730x; 1.4668x over previous
//
#include <hip/hip_runtime.h>
#include <cstddef>

#define HW96 9216
#define FRAME (64 * 9216)

typedef unsigned short ushort_t;
typedef __attribute__((ext_vector_type(8))) short bf16x8;
typedef __attribute__((ext_vector_type(4))) float f32x4;
typedef __attribute__((ext_vector_type(4))) unsigned u32x4;

// packed u32 = (bf16 hi bits << 16) | bf16 lo bits; value = hi + lo exactly
__device__ __forceinline__ float unpk(unsigned p) {
    return __uint_as_float(p & 0xFFFF0000u) + __uint_as_float(p << 16);
}
__device__ __forceinline__ unsigned pk(float v) {
    unsigned u = __float_as_uint(v);
    unsigned hi = u & 0xFFFF0000u;
    float rem = v - __uint_as_float(hi);
    unsigned r = __float_as_uint(rem);
    unsigned lo = (r + 0x7FFFu + ((r >> 16) & 1u)) >> 16;
    return hi | (lo & 0xFFFFu);
}
__device__ __forceinline__ void split16(float v, ushort_t& h, ushort_t& l) {
    unsigned u = __float_as_uint(v);
    h = (ushort_t)(u >> 16);
    float rem = v - __uint_as_float(u & 0xFFFF0000u);
    unsigned r = __float_as_uint(rem);
    l = (ushort_t)((r + 0x7FFFu + ((r >> 16) & 1u)) >> 16);
}

// ---------------------------------------------------------------------------
// Plain repack: OIHW -> [i][o] fp32 (fusion 1x1 only).
// ---------------------------------------------------------------------------
__global__ __launch_bounds__(256) void repack_fus_k(const float* __restrict__ w,
                                                    float* __restrict__ wp) {
    int idx = blockIdx.x * 256 + threadIdx.x;  // 128*64
    if (idx >= 128 * 64) return;
    int o = idx % 64;
    int i = idx / 64;
    wp[idx] = w[o * 128 + i];
}

// ---------------------------------------------------------------------------
// MFMA A-fragment prepack (16x16x32) with bf16 hi/lo split.
// mode 0 (3x3 conv): layout [hl][t][cc][ot][lane][j]; K = cin chunks of 32.
// mode 1 (dconv):    layout [hl][cc][ot][lane][j]; K = g*72 + tap*8 + c.
// A[m=lane&15][k=(lane>>4)*8+j].
// ---------------------------------------------------------------------------
struct FragJob { const float* src; ushort_t* dst; int O, I, OT, KC, mode; };
struct FragJobs { FragJob j[14]; };

__global__ __launch_bounds__(256) void frag_all_k(FragJobs jobs) {
    const FragJob& J = jobs.j[blockIdx.y];
    int idx = blockIdx.x * 256 + threadIdx.x;
    int total = (J.mode ? 1 : 9) * J.KC * J.OT * 512;
    if (idx >= total) return;
    int jj = idx & 7;
    int lane = (idx >> 3) & 63;
    int rem = idx >> 9;
    int ot = rem % J.OT;
    rem /= J.OT;
    int cc = rem % J.KC;
    int t = rem / J.KC;
    int o = ot * 16 + (lane & 15);
    float wv = 0.f;
    if (J.mode == 0) {
        int ci = cc * 32 + (lane >> 4) * 8 + jj;
        if (o < J.O && ci < J.I) wv = J.src[(o * J.I + ci) * 9 + t];
    } else {
        int K = cc * 32 + (lane >> 4) * 8 + jj;
        int g = K / 72, r2 = K % 72;
        int tap = r2 >> 3, c = r2 & 7;
        int ci = g * 8 + c;
        if (o < J.O && ci < J.I) wv = J.src[(o * J.I + ci) * 9 + tap];
    }
    ushort_t h, l;
    split16(wv, h, l);
    J.dst[idx] = h;
    J.dst[total + idx] = l;
}

// ---------------------------------------------------------------------------
// Transposing pack: planar fp32 frames -> interleaved [px][64ch] packed u32.
// Block handles one 64-px x 64-ch tile via padded LDS. grid (144, T).
// ---------------------------------------------------------------------------
__global__ __launch_bounds__(256) void pack_tr_k(const float* __restrict__ src,
                                                 unsigned* __restrict__ dst) {
    const int t = blockIdx.y;
    const int px0 = blockIdx.x * 64;
    __shared__ unsigned tile[64 * 65];
    const float* s = src + (size_t)t * FRAME;
    unsigned* d = dst + (size_t)t * FRAME;
#pragma unroll
    for (int it = 0; it < 16; ++it) {
        int e = it * 256 + threadIdx.x;
        int p = e & 63, ch = e >> 6;
        tile[ch * 65 + p] = pk(s[(size_t)ch * HW96 + px0 + p]);
    }
    __syncthreads();
#pragma unroll
    for (int it = 0; it < 16; ++it) {
        int e = it * 256 + threadIdx.x;
        int ch = e & 63, p = e >> 6;
        d[(size_t)(px0 + p) * 64 + ch] = tile[ch * 65 + p];
    }
}

// ---------------------------------------------------------------------------
// MFMA implicit-GEMM 3x3 conv, 16x16x32 bf16, 3-term hi/lo split.
// Sources are INTERLEAVED [px][64ch] packed u32 -> staging job = 2 contiguous
// u32x4 loads. Block: 256 thr = 4 waves; wave tile = 16 out x 16 px; Cout=64.
// Output interleaved; optional planar fp32 addsrc (dconv residual).
// ---------------------------------------------------------------------------
__global__ __launch_bounds__(256) void convm_k(
    const unsigned* __restrict__ s0, const unsigned* __restrict__ s1,
    const unsigned* __restrict__ s2, int b0, int b1, int b2, int nsrc,
    const ushort_t* __restrict__ wfrag, int KCfull,
    const float* __restrict__ bias, const float* __restrict__ addsrc,
    unsigned* __restrict__ outpk, int act) {
    const int tid = threadIdx.x;
    const int lane = tid & 63;
    const int w = tid >> 6;
    const int xb = (blockIdx.x % 6) * 16;
    const int y = blockIdx.x / 6;
    const int ot = w;
    const int n = lane & 15;
    const int quad = lane >> 4;

    __shared__ __align__(16) ushort_t ldsH[3 * 18 * 72];
    __shared__ __align__(16) ushort_t ldsL[3 * 18 * 72];

    // staging job decode (loop-invariant): 432 jobs = 54 (r,c) x 8 octets
    int jst[2], jok[2], joff[2], jbase[2];
#pragma unroll
    for (int i = 0; i < 2; ++i) {
        int e = tid + i * 256;
        int rc = e >> 3, cg = e & 7;
        int r = rc / 18, col = rc - r * 18;
        int gy = y - 1 + r, gx = xb - 1 + col;
        jst[i] = (e < 432);
        jok[i] = jst[i] && ((unsigned)gy < 96u) && ((unsigned)gx < 96u);
        joff[i] = (gy * 96 + gx) * 64 + cg * 8;
        jbase[i] = rc * 72 + cg * 8;
    }

    f32x4 acc0, acc1;
#pragma unroll
    for (int r = 0; r < 4; ++r) { acc0[r] = 0.f; acc1[r] = 0.f; }

    const size_t hlOff = (size_t)9 * KCfull * 4 * 512;

    for (int j = 0; j < nsrc; ++j) {
        const unsigned* sv = (j == 0) ? s0 : (j == 1 ? s1 : s2);
        const int base = (j == 0) ? b0 : (j == 1 ? b1 : b2);
        __syncthreads();
#pragma unroll
        for (int i = 0; i < 2; ++i) {
            if (jst[i]) {
                u32x4 a, b;
                if (jok[i]) {
                    a = *(const u32x4*)(sv + joff[i]);
                    b = *(const u32x4*)(sv + joff[i] + 4);
                } else {
#pragma unroll
                    for (int q = 0; q < 4; ++q) { a[q] = 0; b[q] = 0; }
                }
                u32x4 H, L;
#pragma unroll
                for (int q = 0; q < 2; ++q) {
                    H[q] = (a[2 * q] >> 16) | (a[2 * q + 1] & 0xFFFF0000u);
                    L[q] = (a[2 * q] & 0xFFFFu) | (a[2 * q + 1] << 16);
                    H[2 + q] = (b[2 * q] >> 16) | (b[2 * q + 1] & 0xFFFF0000u);
                    L[2 + q] = (b[2 * q] & 0xFFFFu) | (b[2 * q + 1] << 16);
                }
                *(u32x4*)(ldsH + jbase[i]) = H;
                *(u32x4*)(ldsL + jbase[i]) = L;
            }
        }
        __syncthreads();
#pragma unroll
        for (int t = 0; t < 9; ++t) {
            const int ky = t / 3, kx = t % 3;
#pragma unroll
            for (int cc2 = 0; cc2 < 2; ++cc2) {
                const int ccor = base + cc2;
                const ushort_t* ab =
                    wfrag + (((size_t)(t * KCfull + ccor) * 4 + ot) * 64 + lane) * 8;
                bf16x8 Ah = *(const bf16x8*)ab;
                bf16x8 Al = *(const bf16x8*)(ab + hlOff);
                int lb = (ky * 18 + n + kx) * 72 + cc2 * 32 + quad * 8;
                bf16x8 Bh = *(const bf16x8*)(ldsH + lb);
                bf16x8 Bl = *(const bf16x8*)(ldsL + lb);
                if (t & 1) {
                    acc1 = __builtin_amdgcn_mfma_f32_16x16x32_bf16(Ah, Bh, acc1, 0, 0, 0);
                    acc1 = __builtin_amdgcn_mfma_f32_16x16x32_bf16(Al, Bh, acc1, 0, 0, 0);
                    acc1 = __builtin_amdgcn_mfma_f32_16x16x32_bf16(Ah, Bl, acc1, 0, 0, 0);
                } else {
                    acc0 = __builtin_amdgcn_mfma_f32_16x16x32_bf16(Ah, Bh, acc0, 0, 0, 0);
                    acc0 = __builtin_amdgcn_mfma_f32_16x16x32_bf16(Al, Bh, acc0, 0, 0, 0);
                    acc0 = __builtin_amdgcn_mfma_f32_16x16x32_bf16(Ah, Bl, acc0, 0, 0, 0);
                }
            }
        }
    }

    const int px = y * 96 + xb + n;
#pragma unroll
    for (int r = 0; r < 4; ++r) {
        int cout = ot * 16 + quad * 4 + r;
        float v = acc0[r] + acc1[r] + bias[cout];
        if (act) v = (v >= 0.f) ? v : 0.1f * v;
        if (addsrc) v += addsrc[(size_t)cout * HW96 + px];
        outpk[(size_t)px * 64 + cout] = pk(v);
    }
}

// ---------------------------------------------------------------------------
// Fused ow4 (64->432 conv) + modulated deformable conv v2.
// Interleaved sources. Block = 256 thr (4 waves), 16-px row segment.
// Phase 1: stage hA 3x18x64 window (hi/lo) in LDS.
// Phase 2: MFMA raw[448][16] (ow4) -> LDS fp32 (stride 17: conflict-free).
// Phase 3: gather (2 u32x4 per corner) -> cols -> dconv MFMA.
// Outputs: planar fp32 (bw2 addsrc) + interleaved packed (bw1 / next gather).
// ---------------------------------------------------------------------------
__global__ __launch_bounds__(256) void dconv_fused_k(
    const unsigned* __restrict__ sA, const unsigned* __restrict__ sB,
    const unsigned* __restrict__ hA, const ushort_t* __restrict__ w4,
    const float* __restrict__ ob4, const ushort_t* __restrict__ dwf,
    const float* __restrict__ dbias, int ngr4, float* __restrict__ outf,
    unsigned* __restrict__ outpk) {
    const int tid = threadIdx.x;
    const int lane = tid & 63;
    const int w = tid >> 6;
    const int xb = (blockIdx.x % 6) * 16;
    const int y = blockIdx.x / 6;
    const int n = lane & 15;
    const int quad = lane >> 4;

    __shared__ __align__(16) char smem[18944 + 448 * 17 * 4];
    ushort_t* ldsAH = (ushort_t*)smem;        // 3888 ushorts
    ushort_t* ldsAL = ldsAH + 3888;
    ushort_t* colsH = (ushort_t*)smem;        // 16*296 ushorts (union)
    ushort_t* colsL = colsH + 4736;
    float* rawS = (float*)(smem + 18944);     // [448][17] fp32

    // ---- phase 1: stage hA window (interleaved source) ----
#pragma unroll
    for (int i = 0; i < 2; ++i) {
        int e = tid + i * 256;
        if (e < 432) {
            int rc = e >> 3, cg = e & 7;
            int r = rc / 18, col = rc - r * 18;
            int gy = y - 1 + r, gx = xb - 1 + col;
            bool ok = ((unsigned)gy < 96u) && ((unsigned)gx < 96u);
            u32x4 a, b;
            if (ok) {
                int off = (gy * 96 + gx) * 64 + cg * 8;
                a = *(const u32x4*)(hA + off);
                b = *(const u32x4*)(hA + off + 4);
            } else {
#pragma unroll
                for (int q = 0; q < 4; ++q) { a[q] = 0; b[q] = 0; }
            }
            u32x4 H, L;
#pragma unroll
            for (int q = 0; q < 2; ++q) {
                H[q] = (a[2 * q] >> 16) | (a[2 * q + 1] & 0xFFFF0000u);
                L[q] = (a[2 * q] & 0xFFFFu) | (a[2 * q + 1] << 16);
                H[2 + q] = (b[2 * q] >> 16) | (b[2 * q + 1] & 0xFFFF0000u);
                L[2 + q] = (b[2 * q] & 0xFFFFu) | (b[2 * q + 1] << 16);
            }
            *(u32x4*)(ldsAH + rc * 72 + cg * 8) = H;
            *(u32x4*)(ldsAL + rc * 72 + cg * 8) = L;
        }
    }
    __syncthreads();

    // ---- phase 2: raw = ow4(hA), 7 out-tiles per wave ----
    const size_t hl4 = (size_t)9 * 2 * 28 * 512;
#pragma unroll 1
    for (int j = 0; j < 7; ++j) {
        const int ot = j * 4 + w;
        f32x4 a0, a1;
#pragma unroll
        for (int r = 0; r < 4; ++r) { a0[r] = 0.f; a1[r] = 0.f; }
#pragma unroll
        for (int t = 0; t < 9; ++t) {
            const int ky = t / 3, kx = t % 3;
#pragma unroll
            for (int cc2 = 0; cc2 < 2; ++cc2) {
                const ushort_t* ab =
                    w4 + (((size_t)(t * 2 + cc2) * 28 + ot) * 64 + lane) * 8;
                bf16x8 Ah = *(const bf16x8*)ab;
                bf16x8 Al = *(const bf16x8*)(ab + hl4);
                int lb = (ky * 18 + n + kx) * 72 + cc2 * 32 + quad * 8;
                bf16x8 Bh = *(const bf16x8*)(ldsAH + lb);
                bf16x8 Bl = *(const bf16x8*)(ldsAL + lb);
                if ((t * 2 + cc2) & 1) {
                    a1 = __builtin_amdgcn_mfma_f32_16x16x32_bf16(Ah, Bh, a1, 0, 0, 0);
                    a1 = __builtin_amdgcn_mfma_f32_16x16x32_bf16(Al, Bh, a1, 0, 0, 0);
                    a1 = __builtin_amdgcn_mfma_f32_16x16x32_bf16(Ah, Bl, a1, 0, 0, 0);
                } else {
                    a0 = __builtin_amdgcn_mfma_f32_16x16x32_bf16(Ah, Bh, a0, 0, 0, 0);
                    a0 = __builtin_amdgcn_mfma_f32_16x16x32_bf16(Al, Bh, a0, 0, 0, 0);
                    a0 = __builtin_amdgcn_mfma_f32_16x16x32_bf16(Ah, Bl, a0, 0, 0, 0);
                }
            }
        }
#pragma unroll
        for (int r = 0; r < 4; ++r) {
            int cout = ot * 16 + quad * 4 + r;
            float v = a0[r] + a1[r] + (cout < 432 ? ob4[cout] : 0.f);
            rawS[cout * 17 + n] = v;
        }
    }

    // ---- phase 3: gather + dconv MFMA ----
    f32x4 acc0, acc1;
#pragma unroll
    for (int r = 0; r < 4; ++r) { acc0[r] = 0.f; acc1[r] = 0.f; }
    const size_t hlD = (size_t)36 * 4 * 512;

    for (int gc = 0; gc < ngr4; ++gc) {
        __syncthreads();  // rawS ready / cols reuse safe
#pragma unroll
        for (int i = 0; i < 3; ++i) {
            int e = tid + i * 256;
            if (e < 576) {
                int p = e & 15;
                int r = e >> 4;  // 0..35
                int gl = r / 9, k = r - gl * 9;
                int g = gc * 4 + gl;
                float ry = rawS[(g * 18 + k * 2 + 0) * 17 + p];
                float rx = rawS[(g * 18 + k * 2 + 1) * 17 + p];
                float rm = rawS[(288 + g * 9 + k) * 17 + p];
                float oy = 5.f * (1.f - 2.f / (1.f + __expf(2.f * ry)));
                float ox = 5.f * (1.f - 2.f / (1.f + __expf(2.f * rx)));
                float m = 1.f / (1.f + __expf(-rm));
                float sy = oy + (float)(y - 1 + k / 3);
                float sx = ox + (float)(xb + p - 1 + k % 3);
                float fy0 = floorf(sy), fx0 = floorf(sx);
                float fy = sy - fy0, fx = sx - fx0;
                int y0 = (int)fy0, x0 = (int)fx0;
                int y1 = y0 + 1, x1 = x0 + 1;
                bool vy0 = (unsigned)y0 < 96u, vy1 = (unsigned)y1 < 96u;
                bool vx0 = (unsigned)x0 < 96u, vx1 = (unsigned)x1 < 96u;
                int cy0 = min(max(y0, 0), 95), cy1 = min(max(y1, 0), 95);
                int cx0 = min(max(x0, 0), 95), cx1 = min(max(x1, 0), 95);
                float w00 = (1.f - fy) * (1.f - fx) * ((vy0 && vx0) ? 1.f : 0.f);
                float w01 = (1.f - fy) * fx * ((vy0 && vx1) ? 1.f : 0.f);
                float w10 = fy * (1.f - fx) * ((vy1 && vx0) ? 1.f : 0.f);
                float w11 = fy * fx * ((vy1 && vx1) ? 1.f : 0.f);
                const unsigned* src = (g < 8) ? sA : sB;
                int cb = (g & 7) * 8;
                int kbase = p * 296 + gl * 72 + k * 8;
                ushort_t hh[8], ll[8];
                if (src) {
                    int b00 = (cy0 * 96 + cx0) * 64 + cb;
                    int b01 = (cy0 * 96 + cx1) * 64 + cb;
                    int b10 = (cy1 * 96 + cx0) * 64 + cb;
                    int b11 = (cy1 * 96 + cx1) * 64 + cb;
                    u32x4 c00a = *(const u32x4*)(src + b00);
                    u32x4 c00b = *(const u32x4*)(src + b00 + 4);
                    u32x4 c01a = *(const u32x4*)(src + b01);
                    u32x4 c01b = *(const u32x4*)(src + b01 + 4);
                    u32x4 c10a = *(const u32x4*)(src + b10);
                    u32x4 c10b = *(const u32x4*)(src + b10 + 4);
                    u32x4 c11a = *(const u32x4*)(src + b11);
                    u32x4 c11b = *(const u32x4*)(src + b11 + 4);
#pragma unroll
                    for (int c = 0; c < 4; ++c) {
                        float v = w00 * unpk(c00a[c]) + w01 * unpk(c01a[c]) +
                                  w10 * unpk(c10a[c]) + w11 * unpk(c11a[c]);
                        split16(v * m, hh[c], ll[c]);
                        float v2 = w00 * unpk(c00b[c]) + w01 * unpk(c01b[c]) +
                                   w10 * unpk(c10b[c]) + w11 * unpk(c11b[c]);
                        split16(v2 * m, hh[4 + c], ll[4 + c]);
                    }
                } else {
#pragma unroll
                    for (int c = 0; c < 8; ++c) { hh[c] = 0; ll[c] = 0; }
                }
                u32x4 H, L;
#pragma unroll
                for (int q = 0; q < 4; ++q) {
                    H[q] = (unsigned)hh[2 * q] | ((unsigned)hh[2 * q + 1] << 16);
                    L[q] = (unsigned)ll[2 * q] | ((unsigned)ll[2 * q + 1] << 16);
                }
                *(u32x4*)(colsH + kbase) = H;
                *(u32x4*)(colsL + kbase) = L;
            }
        }
        __syncthreads();
#pragma unroll
        for (int cc2 = 0; cc2 < 9; ++cc2) {
            int cc = gc * 9 + cc2;
            const ushort_t* ab = dwf + (((size_t)cc * 4 + w) * 64 + lane) * 8;
            bf16x8 Ah = *(const bf16x8*)ab;
            bf16x8 Al = *(const bf16x8*)(ab + hlD);
            int lb = n * 296 + cc2 * 32 + quad * 8;
            bf16x8 Bh = *(const bf16x8*)(colsH + lb);
            bf16x8 Bl = *(const bf16x8*)(colsL + lb);
            if (cc2 & 1) {
                acc1 = __builtin_amdgcn_mfma_f32_16x16x32_bf16(Ah, Bh, acc1, 0, 0, 0);
                acc1 = __builtin_amdgcn_mfma_f32_16x16x32_bf16(Al, Bh, acc1, 0, 0, 0);
                acc1 = __builtin_amdgcn_mfma_f32_16x16x32_bf16(Ah, Bl, acc1, 0, 0, 0);
            } else {
                acc0 = __builtin_amdgcn_mfma_f32_16x16x32_bf16(Ah, Bh, acc0, 0, 0, 0);
                acc0 = __builtin_amdgcn_mfma_f32_16x16x32_bf16(Al, Bh, acc0, 0, 0, 0);
                acc0 = __builtin_amdgcn_mfma_f32_16x16x32_bf16(Ah, Bl, acc0, 0, 0, 0);
            }
        }
    }

    const int pidx = y * 96 + xb + n;
#pragma unroll
    for (int r = 0; r < 4; ++r) {
        int cout = w * 16 + quad * 4 + r;
        float v = acc0[r] + acc1[r] + dbias[cout];
        outf[(size_t)cout * HW96 + pidx] = v;
        outpk[(size_t)pidx * 64 + cout] = pk(v);
    }
}

// ---------------------------------------------------------------------------
// Fusion: 1x1 conv over [featB[t], featF[t]] (interleaved) + bias + x.
// ---------------------------------------------------------------------------
__global__ __launch_bounds__(256) void fuse_k(
    const unsigned* __restrict__ featB, const unsigned* __restrict__ featF,
    const float* __restrict__ x, const float* __restrict__ wp,
    const float* __restrict__ bias, float* __restrict__ out) {
    const int tx = threadIdx.x & 31;
    const int ty = threadIdx.x >> 5;
    const int px = blockIdx.x * 32 + tx;
    const int py = blockIdx.y * 8 + ty;
    const int t = blockIdx.z >> 3;
    const int obase = (blockIdx.z & 7) * 8;
    const int pidx = py * 96 + px;
    const unsigned* fB = featB + (size_t)t * FRAME + (size_t)pidx * 64;
    const unsigned* fF = featF + (size_t)t * FRAME + (size_t)pidx * 64;

    float acc[8];
#pragma unroll
    for (int o = 0; o < 8; ++o) acc[o] = 0.f;

#pragma unroll 4
    for (int i0 = 0; i0 < 64; i0 += 4) {
        u32x4 pv = *(const u32x4*)(fB + i0);
#pragma unroll
        for (int q = 0; q < 4; ++q) {
            float v = unpk(pv[q]);
            const float* wr = wp + (i0 + q) * 64 + obase;
#pragma unroll
            for (int o = 0; o < 8; ++o) acc[o] = fmaf(wr[o], v, acc[o]);
        }
    }
#pragma unroll 4
    for (int i0 = 0; i0 < 64; i0 += 4) {
        u32x4 pv = *(const u32x4*)(fF + i0);
#pragma unroll
        for (int q = 0; q < 4; ++q) {
            float v = unpk(pv[q]);
            const float* wr = wp + (64 + i0 + q) * 64 + obase;
#pragma unroll
            for (int o = 0; o < 8; ++o) acc[o] = fmaf(wr[o], v, acc[o]);
        }
    }
    const float* xt = x + (size_t)t * FRAME;
#pragma unroll
    for (int o = 0; o < 8; ++o)
        out[(size_t)t * FRAME + (size_t)(obase + o) * HW96 + pidx] =
            acc[o] + bias[obase + o] + xt[(size_t)(obase + o) * HW96 + pidx];
}

// ---------------------------------------------------------------------------
extern "C" void kernel_launch(void* const* d_in, const int* in_sizes, int n_in,
                              void* d_out, int out_size, void* d_ws,
                              size_t ws_size, hipStream_t stream) {
    const float* x = (const float*)d_in[0];
    auto gp = [&](int i) { return (const float*)d_in[i]; };

    struct DirP {
        const float *dw, *db, *ow1, *ob1, *ow2, *ob2, *ow3, *ob3, *ow4, *ob4,
            *bw1, *bb1, *bw2, *bb2;
    };
    DirP Pb{gp(1), gp(2), gp(3), gp(4), gp(5), gp(6), gp(7),
            gp(8), gp(9), gp(10), gp(11), gp(12), gp(13), gp(14)};
    DirP Pf{gp(15), gp(16), gp(17), gp(18), gp(19), gp(20), gp(21),
            gp(22), gp(23), gp(24), gp(25), gp(26), gp(27), gp(28)};
    const float* fus_w = gp(29);
    const float* fus_b = gp(30);

    // ---- workspace carve-up (4-byte units); all feature bufs interleaved ----
    unsigned* featBpk = (unsigned*)d_ws;
    unsigned* featFpk = featBpk + (size_t)8 * FRAME;
    unsigned* xpk = featFpk + (size_t)8 * FRAME;
    float* Dbuf = (float*)(xpk + (size_t)8 * FRAME);  // planar fp32
    unsigned* Dpk = (unsigned*)(Dbuf + FRAME);        // interleaved packed
    unsigned* hApk = Dpk + FRAME;
    unsigned* hBpk = hApk + FRAME;
    float* wfus = (float*)(hBpk + FRAME);
    ushort_t* fragp = (ushort_t*)(wfus + 128 * 64);

    auto falloc = [&](size_t nelem) {
        ushort_t* p = fragp;
        fragp += nelem;
        return p;
    };

    // ---- weight prep ----
    repack_fus_k<<<32, 256, 0, stream>>>(fus_w, wfus);

    struct DirW { ushort_t *ow1, *ow2, *ow3, *ow4, *bw1, *bw2, *dw; int bw1KC; };
    FragJobs fj;
    int nf = 0;
    auto fjob = [&](const float* src, int O, int I, int OT, int KC) {
        ushort_t* dst = falloc((size_t)2 * 9 * KC * OT * 512);
        fj.j[nf++] = FragJob{src, dst, O, I, OT, KC, 0};
        return dst;
    };
    auto fjobd = [&](const float* src) {
        ushort_t* dst = falloc((size_t)2 * 36 * 4 * 512);
        fj.j[nf++] = FragJob{src, dst, 64, 128, 4, 36, 1};
        return dst;
    };
    DirW Wb, Wf;
    Wb.ow1 = fjob(Pb.ow1, 64, 192, 4, 6);
    Wb.ow2 = fjob(Pb.ow2, 64, 64, 4, 2);
    Wb.ow3 = fjob(Pb.ow3, 64, 64, 4, 2);
    Wb.ow4 = fjob(Pb.ow4, 432, 64, 28, 2);
    Wb.bw1 = fjob(Pb.bw1, 64, 128, 4, 4);
    Wb.bw1KC = 4;
    Wb.bw2 = fjob(Pb.bw2, 64, 64, 4, 2);
    Wb.dw = fjobd(Pb.dw);
    Wf.ow1 = fjob(Pf.ow1, 64, 192, 4, 6);
    Wf.ow2 = fjob(Pf.ow2, 64, 64, 4, 2);
    Wf.ow3 = fjob(Pf.ow3, 64, 64, 4, 2);
    Wf.ow4 = fjob(Pf.ow4, 432, 64, 28, 2);
    Wf.bw1 = fjob(Pf.bw1, 64, 192, 4, 6);
    Wf.bw1KC = 6;
    Wf.bw2 = fjob(Pf.bw2, 64, 64, 4, 2);
    Wf.dw = fjobd(Pf.dw);
    frag_all_k<<<dim3(1008, 14), 256, 0, stream>>>(fj);

    pack_tr_k<<<dim3(144, 8), 256, 0, stream>>>(x, xpk);

    auto convm = [&](const unsigned* a, const unsigned* b, const unsigned* c2,
                     const ushort_t* frag, int KCfull, const float* bias,
                     const float* addsrc, unsigned* out, int act) {
        const unsigned* srcs[3] = {a, b, c2};
        const unsigned* S[3] = {nullptr, nullptr, nullptr};
        int B[3] = {0, 0, 0};
        int ns = 0;
        for (int j = 0; j < 3; ++j)
            if (srcs[j]) {
                S[ns] = srcs[j];
                B[ns] = j * 2;
                ++ns;
            }
        convm_k<<<576, 256, 0, stream>>>(S[0], S[1], S[2], B[0], B[1], B[2],
                                         ns, frag, KCfull, bias, addsrc, out,
                                         act);
    };

    for (int dir = 0; dir < 2; ++dir) {  // 0 = backward, 1 = forward
        const DirP& P = dir ? Pf : Pb;
        const DirW& W = dir ? Wf : Wb;
        unsigned* feat = dir ? featFpk : featBpk;
        const unsigned* prev1 = nullptr;
        const unsigned* prev2 = nullptr;
        for (int i = 0; i < 8; ++i) {
            int idx = dir ? i : 7 - i;
            const unsigned* cur = xpk + (size_t)idx * FRAME;
            const float* propf = nullptr;
            if (i > 0) {
                convm(prev1, cur, prev2, W.ow1, 6, P.ob1, nullptr, hApk, 1);
                convm(hApk, nullptr, nullptr, W.ow2, 2, P.ob2, nullptr, hBpk, 1);
                convm(hBpk, nullptr, nullptr, W.ow3, 2, P.ob3, nullptr, hApk, 1);
                int ngr4 = (prev2 != nullptr) ? 4 : 2;
                dconv_fused_k<<<576, 256, 0, stream>>>(
                    prev1, prev2, hApk, W.ow4, P.ob4, W.dw, P.db, ngr4, Dbuf,
                    Dpk);
                propf = Dbuf;
            }
            unsigned* dst = feat + (size_t)idx * FRAME;
            if (dir == 0) {
                convm(cur, (i > 0) ? Dpk : nullptr, nullptr, W.bw1, W.bw1KC,
                      P.bb1, nullptr, hBpk, 1);
            } else {
                convm(cur, featBpk + (size_t)idx * FRAME,
                      (i > 0) ? Dpk : nullptr, W.bw1, W.bw1KC, P.bb1, nullptr,
                      hBpk, 1);
            }
            convm(hBpk, nullptr, nullptr, W.bw2, 2, P.bb2, propf, dst, 0);
            prev2 = prev1;
            prev1 = dst;
        }
    }

    fuse_k<<<dim3(3, 12, 64), 256, 0, stream>>>(featBpk, featFpk, x, wfus,
                                                fus_b, (float*)d_out);
}